// Round 6
// baseline (2358.722 us; speedup 1.0000x reference)
//
#include <hip/hip_runtime.h>
#include <stdint.h>
#include <stddef.h>

// LSTM: B=64, H=1024, V=4096, T=256
// Phase 0: transpose weights to bf16 k-contiguous layouts (Wcat c=h*4+g, ywT).
// Phase 1: ONE persistent kernel, 128 WGs x 256 thr, all 256 steps.
//   - W-slice (32 gate-cols, 64KB) resident in LDS for the whole kernel
//   - A (H rows) loaded DIRECTLY global->VGPR per wave (no LDS ring, no
//     s_barriers, no global_load_lds in the K-loop). Normal cached loads:
//     poll-gating guarantees no read-before-write; each Hbuf[t] is written
//     once; 16 WGs/XCD share H_t via L2.
//   - H stores remain sc0|sc1 (write-through to IF) for cross-XCD visibility
//   - per-chunk monotone counters; per-wave parallel polls (lanes 0..3),
//     overlapped with A-load issue; one __syncthreads + one relaxed
//     fetch_add per step. No acquire/release cache maintenance anywhere.
//   - waves m-split (wave owns 16 batch rows, full K); C in registers
// Phase 2: one big 16384x4096x1024 bf16 GEMM for Y.
// Workspace: WcatT 8MB | ywT 8MB | Hbuf (257*64*1024 bf16) 33.7MB | cnt 1KB

#define B_ 64
#define H_ 1024
#define V_ 4096
#define T_ 256
#define NWG 128

typedef __attribute__((ext_vector_type(8))) short short8;
typedef __attribute__((ext_vector_type(4))) float f32x4;
typedef __attribute__((ext_vector_type(4))) float float4_;
typedef __attribute__((ext_vector_type(2))) unsigned int uint2v;

static __device__ __forceinline__ unsigned short f2bf(float f) {
  union { float f; unsigned int u; } v; v.f = f;
  unsigned int u = v.u;
  unsigned int r = (u + 0x7fffu + ((u >> 16) & 1u)) >> 16;   // round-to-nearest-even
  return (unsigned short)r;
}

static __device__ __forceinline__ void gload_lds16(const void* g, void* l) {
  // async global->LDS, 16B per lane; LDS dest = wave-uniform base + lane*16
  __builtin_amdgcn_global_load_lds((const __attribute__((address_space(1))) unsigned int*)g,
                                   (__attribute__((address_space(3))) unsigned int*)l,
                                   16, 0, 0);
}

// ---------------------------------------------------------------------------
// Tiled transpose fp32 (K x C) -> bf16 rows: dst[c = col*c_mul + c_add][k]
// grid: (K/64, C/64), 256 threads
// ---------------------------------------------------------------------------
__global__ void transpose_bf16_kernel(const float* __restrict__ src, int src_cols,
                                      unsigned short* __restrict__ dst,
                                      int c_mul, int c_add) {
  __shared__ float tile[64][65];
  const int k0 = blockIdx.x * 64, h0 = blockIdx.y * 64;
  const int t = threadIdx.x;
  {
    const int kk = t >> 2, seg = (t & 3) * 16;
    const float* s = src + (size_t)(k0 + kk) * src_cols + h0 + seg;
#pragma unroll
    for (int j = 0; j < 16; j += 4) {
      float4_ v = *(const float4_*)(s + j);
      tile[kk][seg + j + 0] = v[0];
      tile[kk][seg + j + 1] = v[1];
      tile[kk][seg + j + 2] = v[2];
      tile[kk][seg + j + 3] = v[3];
    }
  }
  __syncthreads();
  {
    const int hh = t >> 2, ks = (t & 3) * 16;
    const int c = (h0 + hh) * c_mul + c_add;
    short8 p0, p1;
#pragma unroll
    for (int j = 0; j < 8; ++j) {
      p0[j] = (short)f2bf(tile[ks + j][hh]);
      p1[j] = (short)f2bf(tile[ks + 8 + j][hh]);
    }
    unsigned short* d = dst + (size_t)c * 1024 + k0 + ks;
    *(short8*)(d) = p0;
    *(short8*)(d + 8) = p1;
  }
}

// ---------------------------------------------------------------------------
__global__ void init_kernel(const float* __restrict__ H0,
                            unsigned short* __restrict__ Hbuf0,
                            unsigned int* __restrict__ cnt) {
  const int i = blockIdx.x * 256 + threadIdx.x;  // 65536
  Hbuf0[i] = f2bf(H0[i]);
  if (blockIdx.x == 0) cnt[threadIdx.x] = 0;     // zero chunk counters each launch
}

// ---------------------------------------------------------------------------
// Persistent LSTM recurrence. 128 WGs x 256 thr (4 waves). LDS: W 64KB only.
// ---------------------------------------------------------------------------
__launch_bounds__(256, 1)
__global__ void lstm_persistent_kernel(
    const unsigned short* __restrict__ Wcat,   // [4096][1024] bf16
    unsigned short* __restrict__ Hbuf,         // [257][64][1024] bf16
    unsigned int* __restrict__ cnt,            // [16*c] = chunk-c counter, c=0..7
    const float* __restrict__ C0,              // [64][1024] f32
    const float* __restrict__ xwf, const float* __restrict__ xwi,
    const float* __restrict__ xwc, const float* __restrict__ xwo,
    const float* __restrict__ bfv, const float* __restrict__ biv,
    const float* __restrict__ bcv, const float* __restrict__ bov,
    const int* __restrict__ tokens,
    float* __restrict__ outH, float* __restrict__ outC) {
  __shared__ __align__(16) unsigned char lds[65536];
  const int tid = threadIdx.x;
  const int wave = tid >> 6, lane = tid & 63;
  const int l15 = lane & 15, l4 = lane >> 4;
  const int wgc0 = blockIdx.x * 32;
  const int hbase0 = wgc0 >> 2;
  const int mychunk = blockIdx.x >> 4;   // h-chunk this WG's H-slice belongs to

  auto xw_of = [&](int g) -> const float* {
    return g == 0 ? xwf : g == 1 ? xwi : g == 2 ? xwc : xwo;
  };
  auto b_of = [&](int g) -> const float* {
    return g == 0 ? bfv : g == 1 ? biv : g == 2 ? bcv : bov;
  };

  // ---- per-lane constants & persistent register state ----
  // output tile element: row(batch) = wave*16 + l4*4 + r, col = wgc0 + ni*16 + l15
  int hh[2], gg[2];
  float bias_v[2], Creg[2][4], xg[2][4], xgn[2][4];
#pragma unroll
  for (int ni = 0; ni < 2; ++ni) {
    const int col = wgc0 + ni * 16 + l15;
    hh[ni] = col >> 2; gg[ni] = col & 3;
    bias_v[ni] = b_of(gg[ni])[hh[ni]];
#pragma unroll
    for (int r = 0; r < 4; ++r)
      Creg[ni][r] = C0[(size_t)(wave * 16 + l4 * 4 + r) * 1024 + hh[ni]];
  }
  {
    int tk[4];
#pragma unroll
    for (int r = 0; r < 4; ++r) tk[r] = tokens[(wave * 16 + l4 * 4 + r) * T_ + 0];
#pragma unroll
    for (int ni = 0; ni < 2; ++ni)
#pragma unroll
      for (int r = 0; r < 4; ++r)
        xg[ni][r] = xw_of(gg[ni])[(size_t)tk[r] * 1024 + hh[ni]];
  }

  // ---- stage W-slice into LDS (once), pre-swizzled source ----
  {
    const char* Wb = (const char*)(Wcat + (size_t)wgc0 * 1024);
#pragma unroll
    for (int it = 0; it < 16; ++it) {
      const int D = it * 4096 + wave * 1024 + lane * 16;
      const int row = D >> 11, off = D & 2047;
      const int so = off ^ ((row & 7) << 4);
      gload_lds16(Wb + (size_t)row * 2048 + so, &lds[it * 4096 + wave * 1024]);
    }
  }
  asm volatile("s_waitcnt vmcnt(0)" ::: "memory");
  __syncthreads();

  const int arow = wave * 16 + l15;          // this lane's A (batch) row
  const int bswz = (l15 & 7) << 4;
  f32x4 acc[2];
  const f32x4 zz = {0.f, 0.f, 0.f, 0.f};

  // poll helper: lanes 0..3 poll counters base..base+3 against tgt
  auto poll4 = [&](int base, unsigned int tgt) {
    bool ok = (lane >= 4) ||
              (__hip_atomic_load(cnt + 16 * (base + lane), __ATOMIC_RELAXED,
                                 __HIP_MEMORY_SCOPE_AGENT) >= tgt);
    while (!__all(ok)) {
      ok = (lane >= 4) ||
           (__hip_atomic_load(cnt + 16 * (base + lane), __ATOMIC_RELAXED,
                              __HIP_MEMORY_SCOPE_AGENT) >= tgt);
    }
    asm volatile("" ::: "memory");           // no load hoisting above the poll
    __builtin_amdgcn_sched_barrier(0);
  };

#pragma unroll 1
  for (int t = 0; t < T_; ++t) {
    const unsigned int tgt = (unsigned int)(16 * t);
    const char* Arow = (const char*)(Hbuf + (size_t)t * 65536) +
                       (size_t)arow * 2048 + l4 * 16;

    // ---- poll chunks 0..3, issue their A-loads; poll 4..7 overlapped ----
    if (t > 0) poll4(0, tgt);
    short8 areg[8][4];
#pragma unroll
    for (int c = 0; c < 4; ++c)
#pragma unroll
      for (int ks = 0; ks < 4; ++ks)
        areg[c][ks] = *(const short8*)(Arow + c * 256 + ks * 64);

    int tok2[4];
    if (t < T_ - 1) {
#pragma unroll
      for (int r = 0; r < 4; ++r)
        tok2[r] = tokens[(wave * 16 + l4 * 4 + r) * T_ + (t + 1)];
    }

    if (t > 0) poll4(4, tgt);
#pragma unroll
    for (int c = 4; c < 8; ++c)
#pragma unroll
      for (int ks = 0; ks < 4; ++ks)
        areg[c][ks] = *(const short8*)(Arow + c * 256 + ks * 64);

    // ---- K compute: 64 MFMA + 64 ds_read, no barriers, compiler-scheduled ----
    acc[0] = zz; acc[1] = zz;
#pragma unroll
    for (int c = 0; c < 8; ++c) {
#pragma unroll
      for (int ks = 0; ks < 4; ++ks) {
        const int koff = c * 256 + ks * 64 + l4 * 16;
        short8 b0 = *(const short8*)&lds[(size_t)l15 * 2048 + (koff ^ bswz)];
        short8 b1 = *(const short8*)&lds[(size_t)(16 + l15) * 2048 + (koff ^ bswz)];
        acc[0] = __builtin_amdgcn_mfma_f32_16x16x32_bf16(areg[c][ks], b0, acc[0], 0, 0, 0);
        acc[1] = __builtin_amdgcn_mfma_f32_16x16x32_bf16(areg[c][ks], b1, acc[1], 0, 0, 0);
      }
    }

    // xg for this step: t=0 preloaded; t>0 from prefetch issued last iteration
    if (t > 0) {
#pragma unroll
      for (int ni = 0; ni < 2; ++ni)
#pragma unroll
        for (int r = 0; r < 4; ++r) xg[ni][r] = xgn[ni][r];
    }

    // ---- epilogue: gates on all lanes, C in regs, packed sc0sc1 H store ----
    unsigned short* Hout = Hbuf + (size_t)(t + 1) * 65536;
#pragma unroll
    for (int ni = 0; ni < 2; ++ni) {
#pragma unroll
      for (int r = 0; r < 4; ++r) {
        const float pre = acc[ni][r] + xg[ni][r] + bias_v[ni];
        const float p1 = __shfl_down(pre, 1);
        const float p2 = __shfl_down(pre, 2);
        const float p3 = __shfl_down(pre, 3);
        const float pf = 1.f / (1.f + __expf(-pre));
        const float pi = 1.f / (1.f + __expf(-p1));
        const float e2 = __expf(2.f * p2);
        const float pc = (e2 - 1.f) / (e2 + 1.f);
        const float po = 1.f / (1.f + __expf(-p3));
        const float cn = pf * Creg[ni][r] + pi * pc;   // junk on lanes l15%4!=0: never stored
        Creg[ni][r] = cn;
        const float hv = po * cn;
        const unsigned int sbf = f2bf(hv);
        const unsigned int s4 = __shfl_down(sbf, 4);
        const unsigned int s8 = __shfl_down(sbf, 8);
        const unsigned int s12 = __shfl_down(sbf, 12);
        const int row = wave * 16 + l4 * 4 + r;
        if (l15 == 0) {
          uint2v dat; dat.x = sbf | (s4 << 16); dat.y = s8 | (s12 << 16);
          const unsigned long long addr =
              (unsigned long long)(Hout + (size_t)row * 1024 + hbase0 + ni * 4);
          asm volatile("global_store_dwordx2 %0, %1, off sc0 sc1"
                       :: "v"(addr), "v"(dat) : "memory");
        }
        if (t == T_ - 1 && (lane & 3) == 0) {
          const size_t idx = (size_t)row * 1024 + hh[ni];
          outH[idx] = hv; outC[idx] = cn;
        }
      }
    }

    if (t < T_ - 1) {
      // ---- arrive: drain H stores (all waves), one relaxed add per WG ----
      asm volatile("s_waitcnt vmcnt(0)" ::: "memory");
      __syncthreads();
      if (tid == 0)
        __hip_atomic_fetch_add(cnt + 16 * mychunk, 1u, __ATOMIC_RELAXED,
                               __HIP_MEMORY_SCOPE_AGENT);

      // prefetch next-step x-gather (after arrival so it never delays it)
#pragma unroll
      for (int ni = 0; ni < 2; ++ni)
#pragma unroll
        for (int r = 0; r < 4; ++r)
          xgn[ni][r] = xw_of(gg[ni])[(size_t)tok2[r] * 1024 + hh[ni]];
    }
  }
}

// ---------------------------------------------------------------------------
// Y = Hseq(16384x1024 bf16) @ ywT^T + bias -> fp32. m97-style 128x128, BK=32.
// grid: 4096 WGs (tm = id>>5, tn = id&31), 256 thr, waves 2x2, wave tile 64x64.
// ---------------------------------------------------------------------------
__launch_bounds__(256, 1)
__global__ void out_gemm_kernel(const unsigned short* __restrict__ A,   // [16384][1024] bf16
                                const unsigned short* __restrict__ Bw,  // ywT [4096][1024] bf16
                                const float* __restrict__ bias,         // [4096]
                                float* __restrict__ Yout) {             // [16384][4096] f32
  __shared__ unsigned char Ash[2][8192];   // 128 rows x 64B, XOR-swizzled
  __shared__ unsigned char Bsh[2][8192];
  const int tid = threadIdx.x;
  const int wave = tid >> 6, lane = tid & 63;
  const int wm = wave >> 1, wn = wave & 1;
  const int bid = blockIdx.x;
  const int tn = bid & 31, tm = bid >> 5;

  const char* Agb = (const char*)(A + (size_t)tm * 128 * 1024);
  const char* Bgb = (const char*)(Bw + (size_t)tn * 128 * 1024);

  f32x4 acc[4][4];
  const f32x4 zz = {0.f, 0.f, 0.f, 0.f};
#pragma unroll
  for (int mi = 0; mi < 4; ++mi)
#pragma unroll
    for (int ni = 0; ni < 4; ++ni) acc[mi][ni] = zz;

  auto stage = [&](int buf, int kc) {
#pragma unroll
    for (int j = 0; j < 2; ++j) {
      const int wbase = wave * 2048 + j * 1024;
      const int D = wbase + lane * 16;
      const int row = D >> 6, off = D & 63;
      const int so = off ^ ((row & 3) << 4);
      gload_lds16(Agb + (size_t)row * 2048 + kc * 64 + so, &Ash[buf][wbase]);
      gload_lds16(Bgb + (size_t)row * 2048 + kc * 64 + so, &Bsh[buf][wbase]);
    }
  };

  stage(0, 0);
  __syncthreads();

#pragma unroll 1
  for (int kc = 0; kc < 32; ++kc) {
    const int cur = kc & 1;
    if (kc < 31) stage(cur ^ 1, kc + 1);
    short8 a[4], b[4];
#pragma unroll
    for (int mi = 0; mi < 4; ++mi) {
      const int row = wm * 64 + mi * 16 + (lane & 15);
      const int off = ((lane >> 4) * 16) ^ ((row & 3) << 4);
      a[mi] = *(const short8*)&Ash[cur][row * 64 + off];
    }
#pragma unroll
    for (int ni = 0; ni < 4; ++ni) {
      const int row = wn * 64 + ni * 16 + (lane & 15);
      const int off = ((lane >> 4) * 16) ^ ((row & 3) << 4);
      b[ni] = *(const short8*)&Bsh[cur][row * 64 + off];
    }
#pragma unroll
    for (int mi = 0; mi < 4; ++mi)
#pragma unroll
      for (int ni = 0; ni < 4; ++ni)
        acc[mi][ni] = __builtin_amdgcn_mfma_f32_16x16x32_bf16(a[mi], b[ni], acc[mi][ni], 0, 0, 0);
    __syncthreads();
  }

  const int l15 = lane & 15, l4 = lane >> 4;
#pragma unroll
  for (int ni = 0; ni < 4; ++ni) {
    const int n = tn * 128 + wn * 64 + ni * 16 + l15;
    const float bv = bias[n];
#pragma unroll
    for (int mi = 0; mi < 4; ++mi) {
#pragma unroll
      for (int r = 0; r < 4; ++r) {
        const int m = tm * 128 + wm * 64 + mi * 16 + l4 * 4 + r;
        Yout[(size_t)m * 4096 + n] = acc[mi][ni][r] + bv;
      }
    }
  }
}

// ---------------------------------------------------------------------------
extern "C" void kernel_launch(void* const* d_in, const int* in_sizes, int n_in,
                              void* d_out, int out_size, void* d_ws, size_t ws_size,
                              hipStream_t stream) {
  const int* tokens   = (const int*)d_in[0];
  const float* H0     = (const float*)d_in[1];
  const float* C0     = (const float*)d_in[2];
  const float* f_w_xh = (const float*)d_in[3];
  const float* f_w_hh = (const float*)d_in[4];
  const float* f_b    = (const float*)d_in[5];
  const float* i_w_xh = (const float*)d_in[6];
  const float* i_w_hh = (const float*)d_in[7];
  const float* i_b    = (const float*)d_in[8];
  const float* c_w_xh = (const float*)d_in[9];
  const float* c_w_hh = (const float*)d_in[10];
  const float* c_b    = (const float*)d_in[11];
  const float* o_w_xh = (const float*)d_in[12];
  const float* o_w_hh = (const float*)d_in[13];
  const float* o_b    = (const float*)d_in[14];
  const float* y_w_ho = (const float*)d_in[15];
  const float* y_b_o  = (const float*)d_in[16];

  char* ws = (char*)d_ws;
  unsigned short* Wcat = (unsigned short*)ws;                         // 8 MB
  unsigned short* ywT  = (unsigned short*)(ws + (size_t)(8u << 20));  // 8 MB
  unsigned short* Hbuf = (unsigned short*)(ws + (size_t)(16u << 20)); // 257*65536*2 B
  unsigned int* cnt = (unsigned int*)(ws + (size_t)(16u << 20) + (size_t)257 * 65536 * 2);
  const size_t needed = (size_t)(16u << 20) + (size_t)257 * 65536 * 2 + 1024;
  if (ws_size < needed) return;  // workspace too small: fail visibly

  const dim3 thr(256);
  hipLaunchKernelGGL(transpose_bf16_kernel, dim3(16, 16), thr, 0, stream, f_w_hh, 1024, Wcat, 4, 0);
  hipLaunchKernelGGL(transpose_bf16_kernel, dim3(16, 16), thr, 0, stream, i_w_hh, 1024, Wcat, 4, 1);
  hipLaunchKernelGGL(transpose_bf16_kernel, dim3(16, 16), thr, 0, stream, c_w_hh, 1024, Wcat, 4, 2);
  hipLaunchKernelGGL(transpose_bf16_kernel, dim3(16, 16), thr, 0, stream, o_w_hh, 1024, Wcat, 4, 3);
  hipLaunchKernelGGL(transpose_bf16_kernel, dim3(16, 64), thr, 0, stream, y_w_ho, 4096, ywT, 1, 0);
  hipLaunchKernelGGL(init_kernel, dim3(256), thr, 0, stream, H0, Hbuf, cnt);

  float* outH = (float*)d_out + (size_t)T_ * B_ * V_;
  hipLaunchKernelGGL(lstm_persistent_kernel, dim3(NWG), thr, 0, stream,
                     Wcat, Hbuf, cnt, C0,
                     f_w_xh, i_w_xh, c_w_xh, o_w_xh,
                     f_b, i_b, c_b, o_b,
                     tokens, outH, outH + 65536);

  hipLaunchKernelGGL(out_gemm_kernel, dim3(4096), thr, 0, stream,
                     Hbuf + 65536, ywT, y_b_o, (float*)d_out);
}

// Round 8
// 2313.773 us; speedup vs baseline: 1.0194x; 1.0194x over previous
//
#include <hip/hip_runtime.h>
#include <stdint.h>
#include <stddef.h>

// LSTM: B=64, H=1024, V=4096, T=256
// Phase 0: transpose weights to bf16 k-contiguous layouts (Wcat c=h*4+g, ywT).
// Phase 1: ONE fused persistent kernel, 256 WGs x 256 thr (1 WG/CU via 144KB LDS):
//   WGs 0..127  : LSTM recurrence (W-slice in LDS, H ring via global_load_lds,
//                 counted vmcnt, C in registers, sc0|sc1 H stores).
//                 Sync: 8 per-chunk monotone counters; ONE wave-parallel poll
//                 (lanes 0..7) per step; arrival = vmcnt(0)+syncthreads+
//                 relaxed fetch_add (every step, incl. t=255).
//                 NOTE: token loads are UNCONDITIONAL (wrapped index) so the
//                 per-step vmcnt FIFO profile is identical at every t — the
//                 round-7 Cf race was a 4-load undercount at t=T-1.
//   WGs 128..255: Y-GEMM (Hseq @ ywT^T + bias), 128x128 tiles, per-tile gated
//                 by cnt >= 16*(2*tm+2) -> overlaps the recurrence on the
//                 other 128 CUs. Producers never wait on Y-WGs; all 256 WGs
//                 are co-resident (1/CU) -> no deadlock.
// Workspace: WcatT 8MB | ywT 8MB | Hbuf (257*64*1024 bf16) 33.7MB | cnt 1KB

#define B_ 64
#define H_ 1024
#define V_ 4096
#define T_ 256
#define NWG 128

typedef __attribute__((ext_vector_type(8))) short short8;
typedef __attribute__((ext_vector_type(4))) float f32x4;
typedef __attribute__((ext_vector_type(4))) float float4_;
typedef __attribute__((ext_vector_type(2))) unsigned int uint2v;

static __device__ __forceinline__ unsigned short f2bf(float f) {
  union { float f; unsigned int u; } v; v.f = f;
  unsigned int u = v.u;
  unsigned int r = (u + 0x7fffu + ((u >> 16) & 1u)) >> 16;   // round-to-nearest-even
  return (unsigned short)r;
}

static __device__ __forceinline__ void gload_lds16(const void* g, void* l) {
  // async global->LDS, 16B per lane; LDS dest = wave-uniform base + lane*16
  __builtin_amdgcn_global_load_lds((const __attribute__((address_space(1))) unsigned int*)g,
                                   (__attribute__((address_space(3))) unsigned int*)l,
                                   16, 0, 0);
}
static __device__ __forceinline__ void gload_lds16_sc(const void* g, void* l) {
  // same, with SC0|SC1 (CPol 0x11): read at device coherence point (IF)
  __builtin_amdgcn_global_load_lds((const __attribute__((address_space(1))) unsigned int*)g,
                                   (__attribute__((address_space(3))) unsigned int*)l,
                                   16, 0, 17);
}

// wave-parallel poll: lanes 0..7 poll counters 0..7 against tgt, __all exit.
static __device__ __forceinline__ void poll8(unsigned int* cnt, unsigned int tgt, int lane) {
  bool ok = true;
  if (lane < 8)
    ok = __hip_atomic_load(cnt + 16 * lane, __ATOMIC_RELAXED, __HIP_MEMORY_SCOPE_AGENT) >= tgt;
  while (!__all(ok)) {
    if (lane < 8)
      ok = __hip_atomic_load(cnt + 16 * lane, __ATOMIC_RELAXED, __HIP_MEMORY_SCOPE_AGENT) >= tgt;
  }
  asm volatile("" ::: "memory");           // no load hoisting above the poll
  __builtin_amdgcn_sched_barrier(0);
}

// ---------------------------------------------------------------------------
// Tiled transpose fp32 (K x C) -> bf16 rows: dst[c = col*c_mul + c_add][k]
// grid: (K/64, C/64), 256 threads
// ---------------------------------------------------------------------------
__global__ void transpose_bf16_kernel(const float* __restrict__ src, int src_cols,
                                      unsigned short* __restrict__ dst,
                                      int c_mul, int c_add) {
  __shared__ float tile[64][65];
  const int k0 = blockIdx.x * 64, h0 = blockIdx.y * 64;
  const int t = threadIdx.x;
  {
    const int kk = t >> 2, seg = (t & 3) * 16;
    const float* s = src + (size_t)(k0 + kk) * src_cols + h0 + seg;
#pragma unroll
    for (int j = 0; j < 16; j += 4) {
      float4_ v = *(const float4_*)(s + j);
      tile[kk][seg + j + 0] = v[0];
      tile[kk][seg + j + 1] = v[1];
      tile[kk][seg + j + 2] = v[2];
      tile[kk][seg + j + 3] = v[3];
    }
  }
  __syncthreads();
  {
    const int hh = t >> 2, ks = (t & 3) * 16;
    const int c = (h0 + hh) * c_mul + c_add;
    short8 p0, p1;
#pragma unroll
    for (int j = 0; j < 8; ++j) {
      p0[j] = (short)f2bf(tile[ks + j][hh]);
      p1[j] = (short)f2bf(tile[ks + 8 + j][hh]);
    }
    unsigned short* d = dst + (size_t)c * 1024 + k0 + ks;
    *(short8*)(d) = p0;
    *(short8*)(d + 8) = p1;
  }
}

// ---------------------------------------------------------------------------
__global__ void init_kernel(const float* __restrict__ H0,
                            unsigned short* __restrict__ Hbuf0,
                            unsigned int* __restrict__ cnt) {
  const int i = blockIdx.x * 256 + threadIdx.x;  // 65536
  Hbuf0[i] = f2bf(H0[i]);
  if (blockIdx.x == 0) cnt[threadIdx.x] = 0;     // zero chunk counters each launch
}

// ---------------------------------------------------------------------------
// Fused persistent kernel. 256 WGs x 256 thr, 144KB LDS -> 1 WG/CU.
// ---------------------------------------------------------------------------
#define AOFF 65536

__launch_bounds__(256, 1)
__global__ void lstm_fused_kernel(
    const unsigned short* __restrict__ Wcat,   // [4096][1024] bf16
    unsigned short* __restrict__ Hbuf,         // [257][64][1024] bf16
    unsigned int* __restrict__ cnt,            // [16*c] = chunk-c counter, c=0..7
    const float* __restrict__ C0,              // [64][1024] f32
    const float* __restrict__ xwf, const float* __restrict__ xwi,
    const float* __restrict__ xwc, const float* __restrict__ xwo,
    const float* __restrict__ bfv, const float* __restrict__ biv,
    const float* __restrict__ bcv, const float* __restrict__ bov,
    const int* __restrict__ tokens,
    const unsigned short* __restrict__ ywT,    // [4096][1024] bf16
    const float* __restrict__ ybias,           // [4096]
    float* __restrict__ Yout,                  // [16384][4096] f32
    float* __restrict__ outH, float* __restrict__ outC) {
  __shared__ __align__(16) unsigned char lds[147456];
  const int tid = threadIdx.x;
  const int wave = tid >> 6, lane = tid & 63;
  const int l15 = lane & 15, l4 = lane >> 4;

  if (blockIdx.x < NWG) {
    // ===================== LSTM recurrence branch =====================
    const int wgc0 = blockIdx.x * 32;
    const int hbase0 = wgc0 >> 2;
    const int mychunk = blockIdx.x >> 4;

    auto xw_of = [&](int g) -> const float* {
      return g == 0 ? xwf : g == 1 ? xwi : g == 2 ? xwc : xwo;
    };
    auto b_of = [&](int g) -> const float* {
      return g == 0 ? bfv : g == 1 ? biv : g == 2 ? bcv : bov;
    };

    // per-lane constants & persistent register state
    int hh[2], gg[2];
    float bias_v[2], Creg[2][4], xg[2][4], xgn[2][4];
#pragma unroll
    for (int ni = 0; ni < 2; ++ni) {
      const int col = wgc0 + ni * 16 + l15;
      hh[ni] = col >> 2; gg[ni] = col & 3;
      bias_v[ni] = b_of(gg[ni])[hh[ni]];
#pragma unroll
      for (int r = 0; r < 4; ++r)
        Creg[ni][r] = C0[(size_t)(wave * 16 + l4 * 4 + r) * 1024 + hh[ni]];
    }
    {
      int tk[4];
#pragma unroll
      for (int r = 0; r < 4; ++r) tk[r] = tokens[(wave * 16 + l4 * 4 + r) * T_ + 0];
#pragma unroll
      for (int ni = 0; ni < 2; ++ni)
#pragma unroll
        for (int r = 0; r < 4; ++r)
          xg[ni][r] = xw_of(gg[ni])[(size_t)tk[r] * 1024 + hh[ni]];
    }

    // stage W-slice into LDS (once), pre-swizzled source
    {
      const char* Wb = (const char*)(Wcat + (size_t)wgc0 * 1024);
#pragma unroll
      for (int it = 0; it < 16; ++it) {
        const int D = it * 4096 + wave * 1024 + lane * 16;
        const int row = D >> 11, off = D & 2047;
        const int so = off ^ ((row & 7) << 4);
        gload_lds16(Wb + (size_t)row * 2048 + so, &lds[it * 4096 + wave * 1024]);
      }
    }

    auto stageA = [&](int buf, int c, const char* Hsrc) {
#pragma unroll
      for (int it = 0; it < 4; ++it) {
        const int D = it * 4096 + wave * 1024 + lane * 16;
        const int row = D >> 8, off = D & 255;
        const int so = off ^ ((row & 7) << 4);
        gload_lds16_sc(Hsrc + (size_t)row * 2048 + c * 256 + so,
                       &lds[AOFF + buf * 16384 + it * 4096 + wave * 1024]);
      }
    };

    asm volatile("s_waitcnt vmcnt(0)" ::: "memory");
    __syncthreads();

    const int bswz = (l15 & 7) << 4;
    f32x4 acc[2];
    const f32x4 zz = {0.f, 0.f, 0.f, 0.f};

#pragma unroll 1
    for (int t = 0; t < T_; ++t) {
      if (t > 0) poll8(cnt, (unsigned int)(16 * t), lane);   // H_t fully ready

      const char* Hs = (const char*)(Hbuf + (size_t)t * 65536);
      // prologue stages: chunks 0..3 -> bufs 0..3 (16 loads, oldest in FIFO)
      stageA(0, 0, Hs);
      stageA(1, 1, Hs);
      stageA(2, 2, Hs);
      stageA(3, 3, Hs);

      // UNCONDITIONAL token loads (wrapped index; unused at t=T-1) so the
      // vmcnt FIFO profile is the same at every step: 16 stage + 4 tok
      // (+8 xgn from previous step when t>0).
      int tok2[4];
      {
        const int tt = (t + 1) & (T_ - 1);
#pragma unroll
        for (int r = 0; r < 4; ++r)
          tok2[r] = tokens[(wave * 16 + l4 * 4 + r) * T_ + tt];
      }

      acc[0] = zz; acc[1] = zz;
      // K loop: wait -> barrier -> stage -> compute. FIFO counts:
      // pre-loop 20 ops (16 stage + 4 tok, xgn retire first); stage S(c+4)
      // adds 4 after each of the first 4 barriers.
#pragma unroll
      for (int c = 0; c < 8; ++c) {
        if (c < 4)       asm volatile("s_waitcnt vmcnt(16)" ::: "memory");
        else if (c == 4) asm volatile("s_waitcnt vmcnt(12)" ::: "memory");
        else if (c == 5) asm volatile("s_waitcnt vmcnt(8)" ::: "memory");
        else if (c == 6) asm volatile("s_waitcnt vmcnt(4)" ::: "memory");
        else             asm volatile("s_waitcnt vmcnt(0)" ::: "memory");
        __builtin_amdgcn_sched_barrier(0);
        __builtin_amdgcn_s_barrier();
        __builtin_amdgcn_sched_barrier(0);
        if (c < 4) stageA((c + 4) % 5, c + 4, Hs);
        {
          const int abase = AOFF + (c % 5) * 16384;
          const int arow = wave * 16 + l15;
          const int abyte = abase + arow * 256;
          const int aswz = (arow & 7) << 4;
#pragma unroll
          for (int ks = 0; ks < 4; ++ks) {
            const int koff = ks * 64 + l4 * 16;
            short8 a  = *(const short8*)&lds[abyte + (koff ^ aswz)];
            short8 b0 = *(const short8*)&lds[(size_t)l15 * 2048 + ((c * 256 + koff) ^ bswz)];
            short8 b1 = *(const short8*)&lds[(size_t)(16 + l15) * 2048 + ((c * 256 + koff) ^ bswz)];
            acc[0] = __builtin_amdgcn_mfma_f32_16x16x32_bf16(a, b0, acc[0], 0, 0, 0);
            acc[1] = __builtin_amdgcn_mfma_f32_16x16x32_bf16(a, b1, acc[1], 0, 0, 0);
          }
        }
        __builtin_amdgcn_sched_barrier(0);
      }

      if (t > 0) {
#pragma unroll
        for (int ni = 0; ni < 2; ++ni)
#pragma unroll
          for (int r = 0; r < 4; ++r) xg[ni][r] = xgn[ni][r];
      }

      // epilogue: gates on all lanes, C in regs, packed sc0sc1 H store
      unsigned short* Hout = Hbuf + (size_t)(t + 1) * 65536;
#pragma unroll
      for (int ni = 0; ni < 2; ++ni) {
#pragma unroll
        for (int r = 0; r < 4; ++r) {
          const float pre = acc[ni][r] + xg[ni][r] + bias_v[ni];
          const float p1 = __shfl_down(pre, 1);
          const float p2 = __shfl_down(pre, 2);
          const float p3 = __shfl_down(pre, 3);
          const float pf = 1.f / (1.f + __expf(-pre));
          const float pi = 1.f / (1.f + __expf(-p1));
          const float e2 = __expf(2.f * p2);
          const float pc = (e2 - 1.f) / (e2 + 1.f);
          const float po = 1.f / (1.f + __expf(-p3));
          const float cn = pf * Creg[ni][r] + pi * pc;   // junk on lanes l15%4!=0: never stored
          Creg[ni][r] = cn;
          const float hv = po * cn;
          const unsigned int sbf = f2bf(hv);
          const unsigned int s4 = __shfl_down(sbf, 4);
          const unsigned int s8 = __shfl_down(sbf, 8);
          const unsigned int s12 = __shfl_down(sbf, 12);
          const int row = wave * 16 + l4 * 4 + r;
          if (l15 == 0) {
            uint2v dat; dat.x = sbf | (s4 << 16); dat.y = s8 | (s12 << 16);
            const unsigned long long addr =
                (unsigned long long)(Hout + (size_t)row * 1024 + hbase0 + ni * 4);
            asm volatile("global_store_dwordx2 %0, %1, off sc0 sc1"
                         :: "v"(addr), "v"(dat) : "memory");
          }
          if (t == T_ - 1 && (lane & 3) == 0) {
            const size_t idx = (size_t)row * 1024 + hh[ni];
            outH[idx] = hv; outC[idx] = cn;
          }
        }
      }

      // arrive EVERY step (Y-GEMM needs t=255 too): drain + add (no wait on add)
      asm volatile("s_waitcnt vmcnt(0)" ::: "memory");
      __syncthreads();
      if (tid == 0)
        __hip_atomic_fetch_add(cnt + 16 * mychunk, 1u, __ATOMIC_RELAXED,
                               __HIP_MEMORY_SCOPE_AGENT);

      if (t < T_ - 1) {
        // prefetch next-step x-gather (after arrival so it never delays it)
#pragma unroll
        for (int ni = 0; ni < 2; ++ni)
#pragma unroll
          for (int r = 0; r < 4; ++r)
            xgn[ni][r] = xw_of(gg[ni])[(size_t)tok2[r] * 1024 + hh[ni]];
      }
    }
  } else {
    // ===================== Y-GEMM branch (gated) =====================
    // Y = Hseq(16384x1024 bf16) @ ywT^T + bias. 128x128 tiles, BK=32.
    // WG g: tn = g&31, tm = (g>>5) + 4*it, it=0..31. Gate: cnt >= 16*(2tm+2).
    const int g = blockIdx.x - NWG;
    const int tn = g & 31, tm0 = g >> 5;
    const int wm = wave >> 1, wn = wave & 1;
    unsigned char* Ash = lds;            // 2 x 8192
    unsigned char* Bsh = lds + 16384;    // 2 x 8192
    const unsigned short* A = Hbuf + 65536;   // rows = H_1..H_256
    const char* Bgb = (const char*)(ywT + (size_t)tn * 128 * 1024);
    const f32x4 zz = {0.f, 0.f, 0.f, 0.f};

#pragma unroll 1
    for (int it = 0; it < 32; ++it) {
      const int tm = tm0 + 4 * it;
      poll8(cnt, (unsigned int)(16 * (2 * tm + 2)), lane);

      const char* Agb = (const char*)(A + (size_t)tm * 128 * 1024);
      f32x4 acc[4][4];
#pragma unroll
      for (int mi = 0; mi < 4; ++mi)
#pragma unroll
        for (int ni = 0; ni < 4; ++ni) acc[mi][ni] = zz;

      auto stage = [&](int buf, int kc) {
#pragma unroll
        for (int j = 0; j < 2; ++j) {
          const int wbase = wave * 2048 + j * 1024;
          const int D = wbase + lane * 16;
          const int row = D >> 6, off = D & 63;
          const int so = off ^ ((row & 3) << 4);
          gload_lds16(Agb + (size_t)row * 2048 + kc * 64 + so, Ash + buf * 8192 + wbase);
          gload_lds16(Bgb + (size_t)row * 2048 + kc * 64 + so, Bsh + buf * 8192 + wbase);
        }
      };

      stage(0, 0);
      __syncthreads();

#pragma unroll 1
      for (int kc = 0; kc < 32; ++kc) {
        const int cur = kc & 1;
        if (kc < 31) stage(cur ^ 1, kc + 1);
        short8 a[4], b[4];
#pragma unroll
        for (int mi = 0; mi < 4; ++mi) {
          const int row = wm * 64 + mi * 16 + l15;
          const int off = (l4 * 16) ^ ((row & 3) << 4);
          a[mi] = *(const short8*)(Ash + cur * 8192 + row * 64 + off);
        }
#pragma unroll
        for (int ni = 0; ni < 4; ++ni) {
          const int row = wn * 64 + ni * 16 + l15;
          const int off = (l4 * 16) ^ ((row & 3) << 4);
          b[ni] = *(const short8*)(Bsh + cur * 8192 + row * 64 + off);
        }
#pragma unroll
        for (int mi = 0; mi < 4; ++mi)
#pragma unroll
          for (int ni = 0; ni < 4; ++ni)
            acc[mi][ni] = __builtin_amdgcn_mfma_f32_16x16x32_bf16(a[mi], b[ni], acc[mi][ni], 0, 0, 0);
        __syncthreads();
      }

#pragma unroll
      for (int ni = 0; ni < 4; ++ni) {
        const int n = tn * 128 + wn * 64 + ni * 16 + l15;
        const float bv = ybias[n];
#pragma unroll
        for (int mi = 0; mi < 4; ++mi) {
#pragma unroll
          for (int r = 0; r < 4; ++r) {
            const int m = tm * 128 + wm * 64 + mi * 16 + l4 * 4 + r;
            Yout[(size_t)m * 4096 + n] = acc[mi][ni][r] + bv;
          }
        }
      }
    }
  }
}

// ---------------------------------------------------------------------------
extern "C" void kernel_launch(void* const* d_in, const int* in_sizes, int n_in,
                              void* d_out, int out_size, void* d_ws, size_t ws_size,
                              hipStream_t stream) {
  const int* tokens   = (const int*)d_in[0];
  const float* H0     = (const float*)d_in[1];
  const float* C0     = (const float*)d_in[2];
  const float* f_w_xh = (const float*)d_in[3];
  const float* f_w_hh = (const float*)d_in[4];
  const float* f_b    = (const float*)d_in[5];
  const float* i_w_xh = (const float*)d_in[6];
  const float* i_w_hh = (const float*)d_in[7];
  const float* i_b    = (const float*)d_in[8];
  const float* c_w_xh = (const float*)d_in[9];
  const float* c_w_hh = (const float*)d_in[10];
  const float* c_b    = (const float*)d_in[11];
  const float* o_w_xh = (const float*)d_in[12];
  const float* o_w_hh = (const float*)d_in[13];
  const float* o_b    = (const float*)d_in[14];
  const float* y_w_ho = (const float*)d_in[15];
  const float* y_b_o  = (const float*)d_in[16];

  char* ws = (char*)d_ws;
  unsigned short* Wcat = (unsigned short*)ws;                         // 8 MB
  unsigned short* ywT  = (unsigned short*)(ws + (size_t)(8u << 20));  // 8 MB
  unsigned short* Hbuf = (unsigned short*)(ws + (size_t)(16u << 20)); // 257*65536*2 B
  unsigned int* cnt = (unsigned int*)(ws + (size_t)(16u << 20) + (size_t)257 * 65536 * 2);
  const size_t needed = (size_t)(16u << 20) + (size_t)257 * 65536 * 2 + 1024;
  if (ws_size < needed) return;  // workspace too small: fail visibly

  const dim3 thr(256);
  hipLaunchKernelGGL(transpose_bf16_kernel, dim3(16, 16), thr, 0, stream, f_w_hh, 1024, Wcat, 4, 0);
  hipLaunchKernelGGL(transpose_bf16_kernel, dim3(16, 16), thr, 0, stream, i_w_hh, 1024, Wcat, 4, 1);
  hipLaunchKernelGGL(transpose_bf16_kernel, dim3(16, 16), thr, 0, stream, c_w_hh, 1024, Wcat, 4, 2);
  hipLaunchKernelGGL(transpose_bf16_kernel, dim3(16, 16), thr, 0, stream, o_w_hh, 1024, Wcat, 4, 3);
  hipLaunchKernelGGL(transpose_bf16_kernel, dim3(16, 64), thr, 0, stream, y_w_ho, 4096, ywT, 1, 0);
  hipLaunchKernelGGL(init_kernel, dim3(256), thr, 0, stream, H0, Hbuf, cnt);

  float* outH = (float*)d_out + (size_t)T_ * B_ * V_;
  hipLaunchKernelGGL(lstm_fused_kernel, dim3(2 * NWG), thr, 0, stream,
                     Wcat, Hbuf, cnt, C0,
                     f_w_xh, i_w_xh, c_w_xh, o_w_xh,
                     f_b, i_b, c_b, o_b,
                     tokens, ywT, y_b_o, (float*)d_out,
                     outH, outH + 65536);
}

// Round 9
// 1710.368 us; speedup vs baseline: 1.3791x; 1.3528x over previous
//
#include <hip/hip_runtime.h>
#include <stdint.h>
#include <stddef.h>

// LSTM: B=64, H=1024, V=4096, T=256
// Phase 0: transpose weights to bf16 k-contiguous layouts (Wcat c=h*4+g, ywT).
// Phase 1: persistent recurrence kernel, 128 WGs x 256 thr (1 WG/CU, 144KB LDS):
//   - W-slice (32 gate-cols, 64KB) resident in LDS for the whole kernel
//   - A (H rows) streamed via 5-buf LDS ring with PER-WAVE staging: wave w
//     stages exactly the 16 rows it reads -> NO cross-wave LDS sharing ->
//     K-loop has NO s_barriers; per-wave counted vmcnt FIFO (16/16/16/16/
//     12/8/4/0; uniform profile via unconditional wrapped token loads).
//   - H loads/stores use sc0|sc1 (coherent via IF); C in registers.
//   - Sync: 8 per-chunk monotone counters; ONE wave-parallel poll8 per step;
//     arrival = vmcnt(0) + syncthreads + relaxed fetch_add (t<T-1 only).
// Phase 2: separate 16384x4096x1024 bf16 GEMM for Y (un-fused: round 8 showed
//   co-running GEMM traffic adds ~450us of fabric latency to the recurrence).
// Workspace: WcatT 8MB | ywT 8MB | Hbuf (257*64*1024 bf16) 33.7MB | cnt 1KB

#define B_ 64
#define H_ 1024
#define V_ 4096
#define T_ 256
#define NWG 128

typedef __attribute__((ext_vector_type(8))) short short8;
typedef __attribute__((ext_vector_type(4))) float f32x4;
typedef __attribute__((ext_vector_type(4))) float float4_;
typedef __attribute__((ext_vector_type(2))) unsigned int uint2v;

static __device__ __forceinline__ unsigned short f2bf(float f) {
  union { float f; unsigned int u; } v; v.f = f;
  unsigned int u = v.u;
  unsigned int r = (u + 0x7fffu + ((u >> 16) & 1u)) >> 16;   // round-to-nearest-even
  return (unsigned short)r;
}

static __device__ __forceinline__ void gload_lds16(const void* g, void* l) {
  // async global->LDS, 16B per lane; LDS dest = wave-uniform base + lane*16
  __builtin_amdgcn_global_load_lds((const __attribute__((address_space(1))) unsigned int*)g,
                                   (__attribute__((address_space(3))) unsigned int*)l,
                                   16, 0, 0);
}
static __device__ __forceinline__ void gload_lds16_sc(const void* g, void* l) {
  // same, with SC0|SC1 (CPol 0x11): read at device coherence point (IF)
  __builtin_amdgcn_global_load_lds((const __attribute__((address_space(1))) unsigned int*)g,
                                   (__attribute__((address_space(3))) unsigned int*)l,
                                   16, 0, 17);
}

// wave-parallel poll: lanes 0..7 poll counters 0..7 against tgt, __all exit.
static __device__ __forceinline__ void poll8(unsigned int* cnt, unsigned int tgt, int lane) {
  bool ok = true;
  if (lane < 8)
    ok = __hip_atomic_load(cnt + 16 * lane, __ATOMIC_RELAXED, __HIP_MEMORY_SCOPE_AGENT) >= tgt;
  while (!__all(ok)) {
    if (lane < 8)
      ok = __hip_atomic_load(cnt + 16 * lane, __ATOMIC_RELAXED, __HIP_MEMORY_SCOPE_AGENT) >= tgt;
  }
  asm volatile("" ::: "memory");           // no load hoisting above the poll
  __builtin_amdgcn_sched_barrier(0);
}

// ---------------------------------------------------------------------------
// Tiled transpose fp32 (K x C) -> bf16 rows: dst[c = col*c_mul + c_add][k]
// grid: (K/64, C/64), 256 threads
// ---------------------------------------------------------------------------
__global__ void transpose_bf16_kernel(const float* __restrict__ src, int src_cols,
                                      unsigned short* __restrict__ dst,
                                      int c_mul, int c_add) {
  __shared__ float tile[64][65];
  const int k0 = blockIdx.x * 64, h0 = blockIdx.y * 64;
  const int t = threadIdx.x;
  {
    const int kk = t >> 2, seg = (t & 3) * 16;
    const float* s = src + (size_t)(k0 + kk) * src_cols + h0 + seg;
#pragma unroll
    for (int j = 0; j < 16; j += 4) {
      float4_ v = *(const float4_*)(s + j);
      tile[kk][seg + j + 0] = v[0];
      tile[kk][seg + j + 1] = v[1];
      tile[kk][seg + j + 2] = v[2];
      tile[kk][seg + j + 3] = v[3];
    }
  }
  __syncthreads();
  {
    const int hh = t >> 2, ks = (t & 3) * 16;
    const int c = (h0 + hh) * c_mul + c_add;
    short8 p0, p1;
#pragma unroll
    for (int j = 0; j < 8; ++j) {
      p0[j] = (short)f2bf(tile[ks + j][hh]);
      p1[j] = (short)f2bf(tile[ks + 8 + j][hh]);
    }
    unsigned short* d = dst + (size_t)c * 1024 + k0 + ks;
    *(short8*)(d) = p0;
    *(short8*)(d + 8) = p1;
  }
}

// ---------------------------------------------------------------------------
__global__ void init_kernel(const float* __restrict__ H0,
                            unsigned short* __restrict__ Hbuf0,
                            unsigned int* __restrict__ cnt) {
  const int i = blockIdx.x * 256 + threadIdx.x;  // 65536
  Hbuf0[i] = f2bf(H0[i]);
  if (blockIdx.x == 0) cnt[threadIdx.x] = 0;     // zero chunk counters each launch
}

// ---------------------------------------------------------------------------
// Persistent LSTM recurrence. 128 WGs x 256 thr (4 waves).
// LDS: W 64KB @0 | ring 5x16KB @65536 = 144KB.
// ---------------------------------------------------------------------------
#define AOFF 65536

__launch_bounds__(256, 1)
__global__ void lstm_persistent_kernel(
    const unsigned short* __restrict__ Wcat,   // [4096][1024] bf16
    unsigned short* __restrict__ Hbuf,         // [257][64][1024] bf16
    unsigned int* __restrict__ cnt,            // [16*c] = chunk-c counter, c=0..7
    const float* __restrict__ C0,              // [64][1024] f32
    const float* __restrict__ xwf, const float* __restrict__ xwi,
    const float* __restrict__ xwc, const float* __restrict__ xwo,
    const float* __restrict__ bfv, const float* __restrict__ biv,
    const float* __restrict__ bcv, const float* __restrict__ bov,
    const int* __restrict__ tokens,
    float* __restrict__ outH, float* __restrict__ outC) {
  __shared__ __align__(16) unsigned char lds[147456];
  const int tid = threadIdx.x;
  const int wave = tid >> 6, lane = tid & 63;
  const int l15 = lane & 15, l4 = lane >> 4;
  const int wgc0 = blockIdx.x * 32;
  const int hbase0 = wgc0 >> 2;
  const int mychunk = blockIdx.x >> 4;   // h-chunk this WG's H-slice belongs to

  auto xw_of = [&](int g) -> const float* {
    return g == 0 ? xwf : g == 1 ? xwi : g == 2 ? xwc : xwo;
  };
  auto b_of = [&](int g) -> const float* {
    return g == 0 ? bfv : g == 1 ? biv : g == 2 ? bcv : bov;
  };

  // ---- per-lane constants & persistent register state ----
  // output tile element: row(batch) = wave*16 + l4*4 + r, col = wgc0 + ni*16 + l15
  int hh[2], gg[2];
  float bias_v[2], Creg[2][4], xg[2][4], xgn[2][4];
#pragma unroll
  for (int ni = 0; ni < 2; ++ni) {
    const int col = wgc0 + ni * 16 + l15;
    hh[ni] = col >> 2; gg[ni] = col & 3;
    bias_v[ni] = b_of(gg[ni])[hh[ni]];
#pragma unroll
    for (int r = 0; r < 4; ++r)
      Creg[ni][r] = C0[(size_t)(wave * 16 + l4 * 4 + r) * 1024 + hh[ni]];
  }
  {
    int tk[4];
#pragma unroll
    for (int r = 0; r < 4; ++r) tk[r] = tokens[(wave * 16 + l4 * 4 + r) * T_ + 0];
#pragma unroll
    for (int ni = 0; ni < 2; ++ni)
#pragma unroll
      for (int r = 0; r < 4; ++r)
        xg[ni][r] = xw_of(gg[ni])[(size_t)tk[r] * 1024 + hh[ni]];
  }

  // ---- stage W-slice into LDS (once), pre-swizzled source ----
  {
    const char* Wb = (const char*)(Wcat + (size_t)wgc0 * 1024);
#pragma unroll
    for (int it = 0; it < 16; ++it) {
      const int D = it * 4096 + wave * 1024 + lane * 16;
      const int row = D >> 11, off = D & 2047;
      const int so = off ^ ((row & 7) << 4);
      gload_lds16(Wb + (size_t)row * 2048 + so, &lds[it * 4096 + wave * 1024]);
    }
  }
  asm volatile("s_waitcnt vmcnt(0)" ::: "memory");
  __syncthreads();

  // PER-WAVE staging: wave w stages its own 16 rows of chunk c. LDS tile
  // layout identical to before (row*256 + col, XOR-swizzled); only the
  // issue->lane mapping changed. No cross-wave LDS dependency.
  auto stageA = [&](int buf, int c, const char* Hsrc) {
#pragma unroll
    for (int it2 = 0; it2 < 4; ++it2) {
      const int row = wave * 16 + it2 * 4 + l4;       // row this lane loads
      const int so = (l15 * 16) ^ ((row & 7) << 4);   // pre-swizzled source
      gload_lds16_sc(Hsrc + (size_t)row * 2048 + c * 256 + so,
                     &lds[AOFF + buf * 16384 + wave * 4096 + it2 * 1024]);
    }
  };

  const int bswz = (l15 & 7) << 4;
  f32x4 acc[2];
  const f32x4 zz = {0.f, 0.f, 0.f, 0.f};

#pragma unroll 1
  for (int t = 0; t < T_; ++t) {
    if (t > 0) poll8(cnt, (unsigned int)(16 * t), lane);   // H_t fully ready

    const char* Hs = (const char*)(Hbuf + (size_t)t * 65536);
    // prologue stages: chunks 0..3 -> bufs 0..3 (16 loads/wave)
    stageA(0, 0, Hs);
    stageA(1, 1, Hs);
    stageA(2, 2, Hs);
    stageA(3, 3, Hs);

    // UNCONDITIONAL token loads (wrapped index; unused at t=T-1) keep the
    // per-step vmcnt FIFO profile identical at every t (round-7 lesson).
    int tok2[4];
    {
      const int tt = (t + 1) & (T_ - 1);
#pragma unroll
      for (int r = 0; r < 4; ++r)
        tok2[r] = tokens[(wave * 16 + l4 * 4 + r) * T_ + tt];
    }

    acc[0] = zz; acc[1] = zz;
    // Barrier-free K loop. Per-wave FIFO: [xgn x8 oldest][S0..S3 x16][tok x4]
    // then +4 per in-loop stage. Chunk c's stage has exactly 16 newer ops at
    // its wait point for c<4, then 12/8/4/0.
#pragma unroll
    for (int c = 0; c < 8; ++c) {
      if (c < 4)       asm volatile("s_waitcnt vmcnt(16)" ::: "memory");
      else if (c == 4) asm volatile("s_waitcnt vmcnt(12)" ::: "memory");
      else if (c == 5) asm volatile("s_waitcnt vmcnt(8)" ::: "memory");
      else if (c == 6) asm volatile("s_waitcnt vmcnt(4)" ::: "memory");
      else             asm volatile("s_waitcnt vmcnt(0)" ::: "memory");
      __builtin_amdgcn_sched_barrier(0);
      if (c < 4) stageA((c + 4) % 5, c + 4, Hs);
      __builtin_amdgcn_sched_barrier(0);
      {
        const int abase = AOFF + (c % 5) * 16384;
        const int arow = wave * 16 + l15;
        const int abyte = abase + arow * 256;
        const int aswz = (arow & 7) << 4;
#pragma unroll
        for (int ks = 0; ks < 4; ++ks) {
          const int koff = ks * 64 + l4 * 16;
          short8 a  = *(const short8*)&lds[abyte + (koff ^ aswz)];
          short8 b0 = *(const short8*)&lds[(size_t)l15 * 2048 + ((c * 256 + koff) ^ bswz)];
          short8 b1 = *(const short8*)&lds[(size_t)(16 + l15) * 2048 + ((c * 256 + koff) ^ bswz)];
          acc[0] = __builtin_amdgcn_mfma_f32_16x16x32_bf16(a, b0, acc[0], 0, 0, 0);
          acc[1] = __builtin_amdgcn_mfma_f32_16x16x32_bf16(a, b1, acc[1], 0, 0, 0);
        }
      }
      __builtin_amdgcn_sched_barrier(0);
    }

    // xg for this step: t=0 preloaded; t>0 from prefetch issued last iteration
    if (t > 0) {
#pragma unroll
      for (int ni = 0; ni < 2; ++ni)
#pragma unroll
        for (int r = 0; r < 4; ++r) xg[ni][r] = xgn[ni][r];
    }

    // ---- epilogue: gates on all lanes, C in regs, packed sc0sc1 H store ----
    unsigned short* Hout = Hbuf + (size_t)(t + 1) * 65536;
#pragma unroll
    for (int ni = 0; ni < 2; ++ni) {
#pragma unroll
      for (int r = 0; r < 4; ++r) {
        const float pre = acc[ni][r] + xg[ni][r] + bias_v[ni];
        const float p1 = __shfl_down(pre, 1);
        const float p2 = __shfl_down(pre, 2);
        const float p3 = __shfl_down(pre, 3);
        const float pf = 1.f / (1.f + __expf(-pre));
        const float pi = 1.f / (1.f + __expf(-p1));
        const float e2 = __expf(2.f * p2);
        const float pc = (e2 - 1.f) / (e2 + 1.f);
        const float po = 1.f / (1.f + __expf(-p3));
        const float cn = pf * Creg[ni][r] + pi * pc;   // junk on lanes l15%4!=0: never stored
        Creg[ni][r] = cn;
        const float hv = po * cn;
        const unsigned int sbf = f2bf(hv);
        const unsigned int s4 = __shfl_down(sbf, 4);
        const unsigned int s8 = __shfl_down(sbf, 8);
        const unsigned int s12 = __shfl_down(sbf, 12);
        const int row = wave * 16 + l4 * 4 + r;
        if (l15 == 0) {
          uint2v dat; dat.x = sbf | (s4 << 16); dat.y = s8 | (s12 << 16);
          const unsigned long long addr =
              (unsigned long long)(Hout + (size_t)row * 1024 + hbase0 + ni * 4);
          asm volatile("global_store_dwordx2 %0, %1, off sc0 sc1"
                       :: "v"(addr), "v"(dat) : "memory");
        }
        if (t == T_ - 1 && (lane & 3) == 0) {
          const size_t idx = (size_t)row * 1024 + hh[ni];
          outH[idx] = hv; outC[idx] = cn;
        }
      }
    }

    if (t < T_ - 1) {
      // ---- arrive: drain H stores (all waves), one relaxed add per WG ----
      asm volatile("s_waitcnt vmcnt(0)" ::: "memory");
      __syncthreads();
      if (tid == 0)
        __hip_atomic_fetch_add(cnt + 16 * mychunk, 1u, __ATOMIC_RELAXED,
                               __HIP_MEMORY_SCOPE_AGENT);

      // prefetch next-step x-gather (after arrival so it never delays it)
#pragma unroll
      for (int ni = 0; ni < 2; ++ni)
#pragma unroll
        for (int r = 0; r < 4; ++r)
          xgn[ni][r] = xw_of(gg[ni])[(size_t)tok2[r] * 1024 + hh[ni]];
    }
  }
}

// ---------------------------------------------------------------------------
// Y = Hseq(16384x1024 bf16) @ ywT^T + bias -> fp32. m97-style 128x128, BK=32.
// grid: 4096 WGs (tm = id>>5, tn = id&31), 256 thr, waves 2x2, wave tile 64x64.
// ---------------------------------------------------------------------------
__launch_bounds__(256, 1)
__global__ void out_gemm_kernel(const unsigned short* __restrict__ A,   // [16384][1024] bf16
                                const unsigned short* __restrict__ Bw,  // ywT [4096][1024] bf16
                                const float* __restrict__ bias,         // [4096]
                                float* __restrict__ Yout) {             // [16384][4096] f32
  __shared__ unsigned char Ash[2][8192];   // 128 rows x 64B, XOR-swizzled
  __shared__ unsigned char Bsh[2][8192];
  const int tid = threadIdx.x;
  const int wave = tid >> 6, lane = tid & 63;
  const int wm = wave >> 1, wn = wave & 1;
  const int bid = blockIdx.x;
  const int tn = bid & 31, tm = bid >> 5;

  const char* Agb = (const char*)(A + (size_t)tm * 128 * 1024);
  const char* Bgb = (const char*)(Bw + (size_t)tn * 128 * 1024);

  f32x4 acc[4][4];
  const f32x4 zz = {0.f, 0.f, 0.f, 0.f};
#pragma unroll
  for (int mi = 0; mi < 4; ++mi)
#pragma unroll
    for (int ni = 0; ni < 4; ++ni) acc[mi][ni] = zz;

  auto stage = [&](int buf, int kc) {
#pragma unroll
    for (int j = 0; j < 2; ++j) {
      const int wbase = wave * 2048 + j * 1024;
      const int D = wbase + lane * 16;
      const int row = D >> 6, off = D & 63;
      const int so = off ^ ((row & 3) << 4);
      gload_lds16(Agb + (size_t)row * 2048 + kc * 64 + so, &Ash[buf][wbase]);
      gload_lds16(Bgb + (size_t)row * 2048 + kc * 64 + so, &Bsh[buf][wbase]);
    }
  };

  stage(0, 0);
  __syncthreads();

#pragma unroll 1
  for (int kc = 0; kc < 32; ++kc) {
    const int cur = kc & 1;
    if (kc < 31) stage(cur ^ 1, kc + 1);
    short8 a[4], b[4];
#pragma unroll
    for (int mi = 0; mi < 4; ++mi) {
      const int row = wm * 64 + mi * 16 + (lane & 15);
      const int off = ((lane >> 4) * 16) ^ ((row & 3) << 4);
      a[mi] = *(const short8*)&Ash[cur][row * 64 + off];
    }
#pragma unroll
    for (int ni = 0; ni < 4; ++ni) {
      const int row = wn * 64 + ni * 16 + (lane & 15);
      const int off = ((lane >> 4) * 16) ^ ((row & 3) << 4);
      b[ni] = *(const short8*)&Bsh[cur][row * 64 + off];
    }
#pragma unroll
    for (int mi = 0; mi < 4; ++mi)
#pragma unroll
      for (int ni = 0; ni < 4; ++ni)
        acc[mi][ni] = __builtin_amdgcn_mfma_f32_16x16x32_bf16(a[mi], b[ni], acc[mi][ni], 0, 0, 0);
    __syncthreads();
  }

  const int l15 = lane & 15, l4 = lane >> 4;
#pragma unroll
  for (int ni = 0; ni < 4; ++ni) {
    const int n = tn * 128 + wn * 64 + ni * 16 + l15;
    const float bv = bias[n];
#pragma unroll
    for (int mi = 0; mi < 4; ++mi) {
#pragma unroll
      for (int r = 0; r < 4; ++r) {
        const int m = tm * 128 + wm * 64 + mi * 16 + l4 * 4 + r;
        Yout[(size_t)m * 4096 + n] = acc[mi][ni][r] + bv;
      }
    }
  }
}

// ---------------------------------------------------------------------------
extern "C" void kernel_launch(void* const* d_in, const int* in_sizes, int n_in,
                              void* d_out, int out_size, void* d_ws, size_t ws_size,
                              hipStream_t stream) {
  const int* tokens   = (const int*)d_in[0];
  const float* H0     = (const float*)d_in[1];
  const float* C0     = (const float*)d_in[2];
  const float* f_w_xh = (const float*)d_in[3];
  const float* f_w_hh = (const float*)d_in[4];
  const float* f_b    = (const float*)d_in[5];
  const float* i_w_xh = (const float*)d_in[6];
  const float* i_w_hh = (const float*)d_in[7];
  const float* i_b    = (const float*)d_in[8];
  const float* c_w_xh = (const float*)d_in[9];
  const float* c_w_hh = (const float*)d_in[10];
  const float* c_b    = (const float*)d_in[11];
  const float* o_w_xh = (const float*)d_in[12];
  const float* o_w_hh = (const float*)d_in[13];
  const float* o_b    = (const float*)d_in[14];
  const float* y_w_ho = (const float*)d_in[15];
  const float* y_b_o  = (const float*)d_in[16];

  char* ws = (char*)d_ws;
  unsigned short* Wcat = (unsigned short*)ws;                         // 8 MB
  unsigned short* ywT  = (unsigned short*)(ws + (size_t)(8u << 20));  // 8 MB
  unsigned short* Hbuf = (unsigned short*)(ws + (size_t)(16u << 20)); // 257*65536*2 B
  unsigned int* cnt = (unsigned int*)(ws + (size_t)(16u << 20) + (size_t)257 * 65536 * 2);
  const size_t needed = (size_t)(16u << 20) + (size_t)257 * 65536 * 2 + 1024;
  if (ws_size < needed) return;  // workspace too small: fail visibly

  const dim3 thr(256);
  hipLaunchKernelGGL(transpose_bf16_kernel, dim3(16, 16), thr, 0, stream, f_w_hh, 1024, Wcat, 4, 0);
  hipLaunchKernelGGL(transpose_bf16_kernel, dim3(16, 16), thr, 0, stream, i_w_hh, 1024, Wcat, 4, 1);
  hipLaunchKernelGGL(transpose_bf16_kernel, dim3(16, 16), thr, 0, stream, c_w_hh, 1024, Wcat, 4, 2);
  hipLaunchKernelGGL(transpose_bf16_kernel, dim3(16, 16), thr, 0, stream, o_w_hh, 1024, Wcat, 4, 3);
  hipLaunchKernelGGL(transpose_bf16_kernel, dim3(16, 64), thr, 0, stream, y_w_ho, 4096, ywT, 1, 0);
  hipLaunchKernelGGL(init_kernel, dim3(256), thr, 0, stream, H0, Hbuf, cnt);

  float* outH = (float*)d_out + (size_t)T_ * B_ * V_;
  hipLaunchKernelGGL(lstm_persistent_kernel, dim3(NWG), thr, 0, stream,
                     Wcat, Hbuf, cnt, C0,
                     f_w_xh, i_w_xh, c_w_xh, o_w_xh,
                     f_b, i_b, c_b, o_b,
                     tokens, outH, outH + 65536);

  hipLaunchKernelGGL(out_gemm_kernel, dim3(4096), thr, 0, stream,
                     Hbuf + 65536, ywT, y_b_o, (float*)d_out);
}

// Round 10
// 1688.637 us; speedup vs baseline: 1.3968x; 1.0129x over previous
//
#include <hip/hip_runtime.h>
#include <stdint.h>
#include <stddef.h>

// LSTM: B=64, H=1024, V=4096, T=256
// Phase 0: transpose weights to bf16 k-contiguous layouts (Wcat c=h*4+g, ywT).
// Phase 1: persistent recurrence kernel, 128 WGs x 256 thr (1 WG/CU, 96KB LDS):
//   - W-slice held ENTIRELY IN REGISTERS (64 x short8 = 256 VGPR/lane, loaded
//     once from global; fragment layout == old LDS path, swizzles cancelled).
//     K-loop LDS traffic drops 3x (384 -> 128 ds_read_b128/CU/step).
//   - A (H rows) streamed via 5-buf LDS ring with PER-WAVE staging (wave w
//     stages/reads only its 16 rows -> no cross-wave LDS sharing, no
//     s_barriers; per-wave counted vmcnt FIFO 16/16/16/16/12/8/4/0, uniform
//     profile via unconditional wrapped token loads).
//   - H loads/stores use sc0|sc1 (coherent via IF); C in registers.
//   - Sync: 8 per-chunk monotone counters; ONE wave-parallel poll8 per step;
//     arrival = vmcnt(0) + syncthreads + relaxed fetch_add (t<T-1 only).
// Phase 2: separate 16384x4096x1024 bf16 GEMM for Y (round 8: fusing it adds
//   fabric interference to the latency-sensitive recurrence).
// Workspace: WcatT 8MB | ywT 8MB | Hbuf (257*64*1024 bf16) 33.7MB | cnt 1KB

#define B_ 64
#define H_ 1024
#define V_ 4096
#define T_ 256
#define NWG 128

typedef __attribute__((ext_vector_type(8))) short short8;
typedef __attribute__((ext_vector_type(4))) float f32x4;
typedef __attribute__((ext_vector_type(4))) float float4_;
typedef __attribute__((ext_vector_type(2))) unsigned int uint2v;

static __device__ __forceinline__ unsigned short f2bf(float f) {
  union { float f; unsigned int u; } v; v.f = f;
  unsigned int u = v.u;
  unsigned int r = (u + 0x7fffu + ((u >> 16) & 1u)) >> 16;   // round-to-nearest-even
  return (unsigned short)r;
}

static __device__ __forceinline__ void gload_lds16(const void* g, void* l) {
  // async global->LDS, 16B per lane; LDS dest = wave-uniform base + lane*16
  __builtin_amdgcn_global_load_lds((const __attribute__((address_space(1))) unsigned int*)g,
                                   (__attribute__((address_space(3))) unsigned int*)l,
                                   16, 0, 0);
}
static __device__ __forceinline__ void gload_lds16_sc(const void* g, void* l) {
  // same, with SC0|SC1 (CPol 0x11): read at device coherence point (IF)
  __builtin_amdgcn_global_load_lds((const __attribute__((address_space(1))) unsigned int*)g,
                                   (__attribute__((address_space(3))) unsigned int*)l,
                                   16, 0, 17);
}

// wave-parallel poll: lanes 0..7 poll counters 0..7 against tgt, __all exit.
static __device__ __forceinline__ void poll8(unsigned int* cnt, unsigned int tgt, int lane) {
  bool ok = true;
  if (lane < 8)
    ok = __hip_atomic_load(cnt + 16 * lane, __ATOMIC_RELAXED, __HIP_MEMORY_SCOPE_AGENT) >= tgt;
  while (!__all(ok)) {
    if (lane < 8)
      ok = __hip_atomic_load(cnt + 16 * lane, __ATOMIC_RELAXED, __HIP_MEMORY_SCOPE_AGENT) >= tgt;
  }
  asm volatile("" ::: "memory");           // no load hoisting above the poll
  __builtin_amdgcn_sched_barrier(0);
}

// ---------------------------------------------------------------------------
// Tiled transpose fp32 (K x C) -> bf16 rows: dst[c = col*c_mul + c_add][k]
// grid: (K/64, C/64), 256 threads
// ---------------------------------------------------------------------------
__global__ void transpose_bf16_kernel(const float* __restrict__ src, int src_cols,
                                      unsigned short* __restrict__ dst,
                                      int c_mul, int c_add) {
  __shared__ float tile[64][65];
  const int k0 = blockIdx.x * 64, h0 = blockIdx.y * 64;
  const int t = threadIdx.x;
  {
    const int kk = t >> 2, seg = (t & 3) * 16;
    const float* s = src + (size_t)(k0 + kk) * src_cols + h0 + seg;
#pragma unroll
    for (int j = 0; j < 16; j += 4) {
      float4_ v = *(const float4_*)(s + j);
      tile[kk][seg + j + 0] = v[0];
      tile[kk][seg + j + 1] = v[1];
      tile[kk][seg + j + 2] = v[2];
      tile[kk][seg + j + 3] = v[3];
    }
  }
  __syncthreads();
  {
    const int hh = t >> 2, ks = (t & 3) * 16;
    const int c = (h0 + hh) * c_mul + c_add;
    short8 p0, p1;
#pragma unroll
    for (int j = 0; j < 8; ++j) {
      p0[j] = (short)f2bf(tile[ks + j][hh]);
      p1[j] = (short)f2bf(tile[ks + 8 + j][hh]);
    }
    unsigned short* d = dst + (size_t)c * 1024 + k0 + ks;
    *(short8*)(d) = p0;
    *(short8*)(d + 8) = p1;
  }
}

// ---------------------------------------------------------------------------
__global__ void init_kernel(const float* __restrict__ H0,
                            unsigned short* __restrict__ Hbuf0,
                            unsigned int* __restrict__ cnt) {
  const int i = blockIdx.x * 256 + threadIdx.x;  // 65536
  Hbuf0[i] = f2bf(H0[i]);
  if (blockIdx.x == 0) cnt[threadIdx.x] = 0;     // zero chunk counters each launch
}

// ---------------------------------------------------------------------------
// Persistent LSTM recurrence. 128 WGs x 256 thr (4 waves).
// LDS: A-ring 5x16KB = 80KB (declared 96KB to force 1 WG/CU). W in VGPRs.
// ---------------------------------------------------------------------------
__launch_bounds__(256, 1)
__global__ void lstm_persistent_kernel(
    const unsigned short* __restrict__ Wcat,   // [4096][1024] bf16
    unsigned short* __restrict__ Hbuf,         // [257][64][1024] bf16
    unsigned int* __restrict__ cnt,            // [16*c] = chunk-c counter, c=0..7
    const float* __restrict__ C0,              // [64][1024] f32
    const float* __restrict__ xwf, const float* __restrict__ xwi,
    const float* __restrict__ xwc, const float* __restrict__ xwo,
    const float* __restrict__ bfv, const float* __restrict__ biv,
    const float* __restrict__ bcv, const float* __restrict__ bov,
    const int* __restrict__ tokens,
    float* __restrict__ outH, float* __restrict__ outC) {
  __shared__ __align__(16) unsigned char lds[98304];   // ring uses first 80KB
  const int tid = threadIdx.x;
  const int wave = tid >> 6, lane = tid & 63;
  const int l15 = lane & 15, l4 = lane >> 4;
  const int wgc0 = blockIdx.x * 32;
  const int hbase0 = wgc0 >> 2;
  const int mychunk = blockIdx.x >> 4;   // h-chunk this WG's H-slice belongs to

  auto xw_of = [&](int g) -> const float* {
    return g == 0 ? xwf : g == 1 ? xwi : g == 2 ? xwc : xwo;
  };
  auto b_of = [&](int g) -> const float* {
    return g == 0 ? bfv : g == 1 ? biv : g == 2 ? bcv : bov;
  };

  // ---- per-lane constants & persistent register state ----
  // output tile element: row(batch) = wave*16 + l4*4 + r, col = wgc0 + ni*16 + l15
  int hh[2], gg[2];
  float bias_v[2], Creg[2][4], xg[2][4], xgn[2][4];
#pragma unroll
  for (int ni = 0; ni < 2; ++ni) {
    const int col = wgc0 + ni * 16 + l15;
    hh[ni] = col >> 2; gg[ni] = col & 3;
    bias_v[ni] = b_of(gg[ni])[hh[ni]];
#pragma unroll
    for (int r = 0; r < 4; ++r)
      Creg[ni][r] = C0[(size_t)(wave * 16 + l4 * 4 + r) * 1024 + hh[ni]];
  }
  {
    int tk[4];
#pragma unroll
    for (int r = 0; r < 4; ++r) tk[r] = tokens[(wave * 16 + l4 * 4 + r) * T_ + 0];
#pragma unroll
    for (int ni = 0; ni < 2; ++ni)
#pragma unroll
      for (int r = 0; r < 4; ++r)
        xg[ni][r] = xw_of(gg[ni])[(size_t)tk[r] * 1024 + hh[ni]];
  }

  // ---- load W fragments into REGISTERS (once, 64 x short8 = 256 VGPR) ----
  // wreg[ni][c][ks] = B-fragment: col = wgc0 + ni*16 + l15,
  //                   k elements = c*128 + ks*32 + l4*8 .. +8  (bf16 x8)
  short8 wreg[2][8][4];
#pragma unroll
  for (int ni = 0; ni < 2; ++ni) {
    const unsigned short* wc = Wcat + (size_t)(wgc0 + ni * 16 + l15) * 1024 + l4 * 8;
#pragma unroll
    for (int c = 0; c < 8; ++c)
#pragma unroll
      for (int ks = 0; ks < 4; ++ks)
        wreg[ni][c][ks] = *(const short8*)(wc + c * 128 + ks * 32);
  }

  // PER-WAVE staging: wave w stages its own 16 rows of chunk c (A ring).
  auto stageA = [&](int buf, int c, const char* Hsrc) {
#pragma unroll
    for (int it2 = 0; it2 < 4; ++it2) {
      const int row = wave * 16 + it2 * 4 + l4;       // row this lane loads
      const int so = (l15 * 16) ^ ((row & 7) << 4);   // pre-swizzled source
      gload_lds16_sc(Hsrc + (size_t)row * 2048 + c * 256 + so,
                     &lds[buf * 16384 + wave * 4096 + it2 * 1024]);
    }
  };

  // one-time drain: clears wreg/constant loads so per-iter vmcnt counts hold
  asm volatile("s_waitcnt vmcnt(0)" ::: "memory");

  f32x4 acc[2];
  const f32x4 zz = {0.f, 0.f, 0.f, 0.f};

#pragma unroll 1
  for (int t = 0; t < T_; ++t) {
    if (t > 0) poll8(cnt, (unsigned int)(16 * t), lane);   // H_t fully ready

    const char* Hs = (const char*)(Hbuf + (size_t)t * 65536);
    // prologue stages: chunks 0..3 -> bufs 0..3 (16 loads/wave)
    stageA(0, 0, Hs);
    stageA(1, 1, Hs);
    stageA(2, 2, Hs);
    stageA(3, 3, Hs);

    // UNCONDITIONAL token loads (wrapped index; unused at t=T-1) keep the
    // per-step vmcnt FIFO profile identical at every t (round-7 lesson).
    int tok2[4];
    {
      const int tt = (t + 1) & (T_ - 1);
#pragma unroll
      for (int r = 0; r < 4; ++r)
        tok2[r] = tokens[(wave * 16 + l4 * 4 + r) * T_ + tt];
    }

    acc[0] = zz; acc[1] = zz;
    // Barrier-free K loop. Per-wave FIFO: [xgn x8 oldest][S0..S3 x16][tok x4]
    // then +4 per in-loop stage. Chunk c's stage has exactly 16 newer ops at
    // its wait point for c<4, then 12/8/4/0.
#pragma unroll
    for (int c = 0; c < 8; ++c) {
      if (c < 4)       asm volatile("s_waitcnt vmcnt(16)" ::: "memory");
      else if (c == 4) asm volatile("s_waitcnt vmcnt(12)" ::: "memory");
      else if (c == 5) asm volatile("s_waitcnt vmcnt(8)" ::: "memory");
      else if (c == 6) asm volatile("s_waitcnt vmcnt(4)" ::: "memory");
      else             asm volatile("s_waitcnt vmcnt(0)" ::: "memory");
      __builtin_amdgcn_sched_barrier(0);
      if (c < 4) stageA((c + 4) % 5, c + 4, Hs);
      __builtin_amdgcn_sched_barrier(0);
      {
        const int abase = (c % 5) * 16384;
        const int arow = wave * 16 + l15;
        const int abyte = abase + arow * 256;
        const int aswz = (arow & 7) << 4;
#pragma unroll
        for (int ks = 0; ks < 4; ++ks) {
          const int koff = ks * 64 + l4 * 16;
          short8 a = *(const short8*)&lds[abyte + (koff ^ aswz)];
          acc[0] = __builtin_amdgcn_mfma_f32_16x16x32_bf16(a, wreg[0][c][ks], acc[0], 0, 0, 0);
          acc[1] = __builtin_amdgcn_mfma_f32_16x16x32_bf16(a, wreg[1][c][ks], acc[1], 0, 0, 0);
        }
      }
      __builtin_amdgcn_sched_barrier(0);
    }

    // xg for this step: t=0 preloaded; t>0 from prefetch issued last iteration
    if (t > 0) {
#pragma unroll
      for (int ni = 0; ni < 2; ++ni)
#pragma unroll
        for (int r = 0; r < 4; ++r) xg[ni][r] = xgn[ni][r];
    }

    // ---- epilogue: gates on all lanes, C in regs, packed sc0sc1 H store ----
    unsigned short* Hout = Hbuf + (size_t)(t + 1) * 65536;
#pragma unroll
    for (int ni = 0; ni < 2; ++ni) {
#pragma unroll
      for (int r = 0; r < 4; ++r) {
        const float pre = acc[ni][r] + xg[ni][r] + bias_v[ni];
        const float p1 = __shfl_down(pre, 1);
        const float p2 = __shfl_down(pre, 2);
        const float p3 = __shfl_down(pre, 3);
        const float pf = 1.f / (1.f + __expf(-pre));
        const float pi = 1.f / (1.f + __expf(-p1));
        const float e2 = __expf(2.f * p2);
        const float pc = (e2 - 1.f) / (e2 + 1.f);
        const float po = 1.f / (1.f + __expf(-p3));
        const float cn = pf * Creg[ni][r] + pi * pc;   // junk on lanes l15%4!=0: never stored
        Creg[ni][r] = cn;
        const float hv = po * cn;
        const unsigned int sbf = f2bf(hv);
        const unsigned int s4 = __shfl_down(sbf, 4);
        const unsigned int s8 = __shfl_down(sbf, 8);
        const unsigned int s12 = __shfl_down(sbf, 12);
        const int row = wave * 16 + l4 * 4 + r;
        if (l15 == 0) {
          uint2v dat; dat.x = sbf | (s4 << 16); dat.y = s8 | (s12 << 16);
          const unsigned long long addr =
              (unsigned long long)(Hout + (size_t)row * 1024 + hbase0 + ni * 4);
          asm volatile("global_store_dwordx2 %0, %1, off sc0 sc1"
                       :: "v"(addr), "v"(dat) : "memory");
        }
        if (t == T_ - 1 && (lane & 3) == 0) {
          const size_t idx = (size_t)row * 1024 + hh[ni];
          outH[idx] = hv; outC[idx] = cn;
        }
      }
    }

    if (t < T_ - 1) {
      // ---- arrive: drain H stores (all waves), one relaxed add per WG ----
      asm volatile("s_waitcnt vmcnt(0)" ::: "memory");
      __syncthreads();
      if (tid == 0)
        __hip_atomic_fetch_add(cnt + 16 * mychunk, 1u, __ATOMIC_RELAXED,
                               __HIP_MEMORY_SCOPE_AGENT);

      // prefetch next-step x-gather (after arrival so it never delays it)
#pragma unroll
      for (int ni = 0; ni < 2; ++ni)
#pragma unroll
        for (int r = 0; r < 4; ++r)
          xgn[ni][r] = xw_of(gg[ni])[(size_t)tok2[r] * 1024 + hh[ni]];
    }
  }
}

// ---------------------------------------------------------------------------
// Y = Hseq(16384x1024 bf16) @ ywT^T + bias -> fp32. m97-style 128x128, BK=32.
// grid: 4096 WGs (tm = id>>5, tn = id&31), 256 thr, waves 2x2, wave tile 64x64.
// ---------------------------------------------------------------------------
__launch_bounds__(256, 1)
__global__ void out_gemm_kernel(const unsigned short* __restrict__ A,   // [16384][1024] bf16
                                const unsigned short* __restrict__ Bw,  // ywT [4096][1024] bf16
                                const float* __restrict__ bias,         // [4096]
                                float* __restrict__ Yout) {             // [16384][4096] f32
  __shared__ unsigned char Ash[2][8192];   // 128 rows x 64B, XOR-swizzled
  __shared__ unsigned char Bsh[2][8192];
  const int tid = threadIdx.x;
  const int wave = tid >> 6, lane = tid & 63;
  const int wm = wave >> 1, wn = wave & 1;
  const int bid = blockIdx.x;
  const int tn = bid & 31, tm = bid >> 5;

  const char* Agb = (const char*)(A + (size_t)tm * 128 * 1024);
  const char* Bgb = (const char*)(Bw + (size_t)tn * 128 * 1024);

  f32x4 acc[4][4];
  const f32x4 zz = {0.f, 0.f, 0.f, 0.f};
#pragma unroll
  for (int mi = 0; mi < 4; ++mi)
#pragma unroll
    for (int ni = 0; ni < 4; ++ni) acc[mi][ni] = zz;

  auto stage = [&](int buf, int kc) {
#pragma unroll
    for (int j = 0; j < 2; ++j) {
      const int wbase = wave * 2048 + j * 1024;
      const int D = wbase + lane * 16;
      const int row = D >> 6, off = D & 63;
      const int so = off ^ ((row & 3) << 4);
      gload_lds16(Agb + (size_t)row * 2048 + kc * 64 + so, &Ash[buf][wbase]);
      gload_lds16(Bgb + (size_t)row * 2048 + kc * 64 + so, &Bsh[buf][wbase]);
    }
  };

  stage(0, 0);
  __syncthreads();

#pragma unroll 1
  for (int kc = 0; kc < 32; ++kc) {
    const int cur = kc & 1;
    if (kc < 31) stage(cur ^ 1, kc + 1);
    short8 a[4], b[4];
#pragma unroll
    for (int mi = 0; mi < 4; ++mi) {
      const int row = wm * 64 + mi * 16 + (lane & 15);
      const int off = ((lane >> 4) * 16) ^ ((row & 3) << 4);
      a[mi] = *(const short8*)&Ash[cur][row * 64 + off];
    }
#pragma unroll
    for (int ni = 0; ni < 4; ++ni) {
      const int row = wn * 64 + ni * 16 + (lane & 15);
      const int off = ((lane >> 4) * 16) ^ ((row & 3) << 4);
      b[ni] = *(const short8*)&Bsh[cur][row * 64 + off];
    }
#pragma unroll
    for (int mi = 0; mi < 4; ++mi)
#pragma unroll
      for (int ni = 0; ni < 4; ++ni)
        acc[mi][ni] = __builtin_amdgcn_mfma_f32_16x16x32_bf16(a[mi], b[ni], acc[mi][ni], 0, 0, 0);
    __syncthreads();
  }

  const int l15 = lane & 15, l4 = lane >> 4;
#pragma unroll
  for (int ni = 0; ni < 4; ++ni) {
    const int n = tn * 128 + wn * 64 + ni * 16 + l15;
    const float bv = bias[n];
#pragma unroll
    for (int mi = 0; mi < 4; ++mi) {
#pragma unroll
      for (int r = 0; r < 4; ++r) {
        const int m = tm * 128 + wm * 64 + mi * 16 + l4 * 4 + r;
        Yout[(size_t)m * 4096 + n] = acc[mi][ni][r] + bv;
      }
    }
  }
}

// ---------------------------------------------------------------------------
extern "C" void kernel_launch(void* const* d_in, const int* in_sizes, int n_in,
                              void* d_out, int out_size, void* d_ws, size_t ws_size,
                              hipStream_t stream) {
  const int* tokens   = (const int*)d_in[0];
  const float* H0     = (const float*)d_in[1];
  const float* C0     = (const float*)d_in[2];
  const float* f_w_xh = (const float*)d_in[3];
  const float* f_w_hh = (const float*)d_in[4];
  const float* f_b    = (const float*)d_in[5];
  const float* i_w_xh = (const float*)d_in[6];
  const float* i_w_hh = (const float*)d_in[7];
  const float* i_b    = (const float*)d_in[8];
  const float* c_w_xh = (const float*)d_in[9];
  const float* c_w_hh = (const float*)d_in[10];
  const float* c_b    = (const float*)d_in[11];
  const float* o_w_xh = (const float*)d_in[12];
  const float* o_w_hh = (const float*)d_in[13];
  const float* o_b    = (const float*)d_in[14];
  const float* y_w_ho = (const float*)d_in[15];
  const float* y_b_o  = (const float*)d_in[16];

  char* ws = (char*)d_ws;
  unsigned short* Wcat = (unsigned short*)ws;                         // 8 MB
  unsigned short* ywT  = (unsigned short*)(ws + (size_t)(8u << 20));  // 8 MB
  unsigned short* Hbuf = (unsigned short*)(ws + (size_t)(16u << 20)); // 257*65536*2 B
  unsigned int* cnt = (unsigned int*)(ws + (size_t)(16u << 20) + (size_t)257 * 65536 * 2);
  const size_t needed = (size_t)(16u << 20) + (size_t)257 * 65536 * 2 + 1024;
  if (ws_size < needed) return;  // workspace too small: fail visibly

  const dim3 thr(256);
  hipLaunchKernelGGL(transpose_bf16_kernel, dim3(16, 16), thr, 0, stream, f_w_hh, 1024, Wcat, 4, 0);
  hipLaunchKernelGGL(transpose_bf16_kernel, dim3(16, 16), thr, 0, stream, i_w_hh, 1024, Wcat, 4, 1);
  hipLaunchKernelGGL(transpose_bf16_kernel, dim3(16, 16), thr, 0, stream, c_w_hh, 1024, Wcat, 4, 2);
  hipLaunchKernelGGL(transpose_bf16_kernel, dim3(16, 16), thr, 0, stream, o_w_hh, 1024, Wcat, 4, 3);
  hipLaunchKernelGGL(transpose_bf16_kernel, dim3(16, 64), thr, 0, stream, y_w_ho, 4096, ywT, 1, 0);
  hipLaunchKernelGGL(init_kernel, dim3(256), thr, 0, stream, H0, Hbuf, cnt);

  float* outH = (float*)d_out + (size_t)T_ * B_ * V_;
  hipLaunchKernelGGL(lstm_persistent_kernel, dim3(NWG), thr, 0, stream,
                     Wcat, Hbuf, cnt, C0,
                     f_w_xh, i_w_xh, c_w_xh, o_w_xh,
                     f_b, i_b, c_b, o_b,
                     tokens, outH, outH + 65536);

  hipLaunchKernelGGL(out_gemm_kernel, dim3(4096), thr, 0, stream,
                     Hbuf + 65536, ywT, y_b_o, (float*)d_out);
}

// Round 11
// 1596.231 us; speedup vs baseline: 1.4777x; 1.0579x over previous
//
#include <hip/hip_runtime.h>
#include <stdint.h>
#include <stddef.h>

// LSTM: B=64, H=1024, V=4096, T=256
// Phase 0: transpose weights to bf16 k-contiguous layouts (Wcat c=h*4+g, ywT).
// Phase 1: persistent recurrence kernel, 128 WGs x 256 thr (1 WG/CU, 144KB LDS):
//   - W-slice (32 gate-cols, 64KB) resident in LDS (reverted from regs: round
//     10 showed the compiler rematerializes >256-VGPR arrays as in-loop global
//     loads, which also corrupts the hand-counted vmcnt FIFO).
//   - MFMA computes mfma(W,H): D rows = gate-cols, cols = batch. r=0..3 of the
//     acc = f,i,c,o of ONE h in ONE lane -> epilogue has no pre-shuffles,
//     8 exp/lane (was 32), 4 pack-shuffles/wave (was 48), one 16B H-store per
//     batch row (was 8x8B). Fragments are byte-identical to the old operand
//     order (verified index algebra) -> bit-identical results.
//   - A (H rows) streamed via 5-buf LDS ring, PER-WAVE staging, NORMAL cached
//     loads (L2-shared within XCD; coherent: poll-gated RAW, write-once
//     addresses, dispatch-start inv — validated empirically in round 6).
//     H stores remain sc0|sc1 (write-through IF for cross-XCD visibility).
//   - Barrier-free K loop; per-wave vmcnt FIFO 13/13/13/13/12/8/4/0
//     (16 stages + 1 tok; sched_barrier-pinned order).
//   - Sync: 8 per-chunk monotone counters; ONE wave-parallel poll8 per step;
//     arrival = vmcnt(0) + syncthreads + relaxed fetch_add (t<T-1 only).
// Phase 2: separate 16384x4096x1024 bf16 GEMM for Y.
// Workspace: WcatT 8MB | ywT 8MB | Hbuf (257*64*1024 bf16) 33.7MB | cnt 1KB

#define B_ 64
#define H_ 1024
#define V_ 4096
#define T_ 256
#define NWG 128

typedef __attribute__((ext_vector_type(8))) short short8;
typedef __attribute__((ext_vector_type(4))) float f32x4;
typedef __attribute__((ext_vector_type(4))) float float4_;
typedef __attribute__((ext_vector_type(4))) unsigned int uint4v;

static __device__ __forceinline__ unsigned short f2bf(float f) {
  union { float f; unsigned int u; } v; v.f = f;
  unsigned int u = v.u;
  unsigned int r = (u + 0x7fffu + ((u >> 16) & 1u)) >> 16;   // round-to-nearest-even
  return (unsigned short)r;
}

static __device__ __forceinline__ void gload_lds16(const void* g, void* l) {
  // async global->LDS, 16B per lane; LDS dest = wave-uniform base + lane*16
  __builtin_amdgcn_global_load_lds((const __attribute__((address_space(1))) unsigned int*)g,
                                   (__attribute__((address_space(3))) unsigned int*)l,
                                   16, 0, 0);
}

// wave-parallel poll: lanes 0..7 poll counters 0..7 against tgt, __all exit.
static __device__ __forceinline__ void poll8(unsigned int* cnt, unsigned int tgt, int lane) {
  bool ok = true;
  if (lane < 8)
    ok = __hip_atomic_load(cnt + 16 * lane, __ATOMIC_RELAXED, __HIP_MEMORY_SCOPE_AGENT) >= tgt;
  while (!__all(ok)) {
    if (lane < 8)
      ok = __hip_atomic_load(cnt + 16 * lane, __ATOMIC_RELAXED, __HIP_MEMORY_SCOPE_AGENT) >= tgt;
  }
  asm volatile("" ::: "memory");           // no load hoisting above the poll
  __builtin_amdgcn_sched_barrier(0);
}

// ---------------------------------------------------------------------------
// Tiled transpose fp32 (K x C) -> bf16 rows: dst[c = col*c_mul + c_add][k]
// grid: (K/64, C/64), 256 threads
// ---------------------------------------------------------------------------
__global__ void transpose_bf16_kernel(const float* __restrict__ src, int src_cols,
                                      unsigned short* __restrict__ dst,
                                      int c_mul, int c_add) {
  __shared__ float tile[64][65];
  const int k0 = blockIdx.x * 64, h0 = blockIdx.y * 64;
  const int t = threadIdx.x;
  {
    const int kk = t >> 2, seg = (t & 3) * 16;
    const float* s = src + (size_t)(k0 + kk) * src_cols + h0 + seg;
#pragma unroll
    for (int j = 0; j < 16; j += 4) {
      float4_ v = *(const float4_*)(s + j);
      tile[kk][seg + j + 0] = v[0];
      tile[kk][seg + j + 1] = v[1];
      tile[kk][seg + j + 2] = v[2];
      tile[kk][seg + j + 3] = v[3];
    }
  }
  __syncthreads();
  {
    const int hh = t >> 2, ks = (t & 3) * 16;
    const int c = (h0 + hh) * c_mul + c_add;
    short8 p0, p1;
#pragma unroll
    for (int j = 0; j < 8; ++j) {
      p0[j] = (short)f2bf(tile[ks + j][hh]);
      p1[j] = (short)f2bf(tile[ks + 8 + j][hh]);
    }
    unsigned short* d = dst + (size_t)c * 1024 + k0 + ks;
    *(short8*)(d) = p0;
    *(short8*)(d + 8) = p1;
  }
}

// ---------------------------------------------------------------------------
__global__ void init_kernel(const float* __restrict__ H0,
                            unsigned short* __restrict__ Hbuf0,
                            unsigned int* __restrict__ cnt) {
  const int i = blockIdx.x * 256 + threadIdx.x;  // 65536
  Hbuf0[i] = f2bf(H0[i]);
  if (blockIdx.x == 0) cnt[threadIdx.x] = 0;     // zero chunk counters each launch
}

// ---------------------------------------------------------------------------
// Persistent LSTM recurrence. 128 WGs x 256 thr (4 waves).
// LDS: W 64KB @0 | ring 5x16KB @65536 = 144KB.
// ---------------------------------------------------------------------------
#define AOFF 65536

__launch_bounds__(256, 1)
__global__ void lstm_persistent_kernel(
    const unsigned short* __restrict__ Wcat,   // [4096][1024] bf16
    unsigned short* __restrict__ Hbuf,         // [257][64][1024] bf16
    unsigned int* __restrict__ cnt,            // [16*c] = chunk-c counter, c=0..7
    const float* __restrict__ C0,              // [64][1024] f32
    const float* __restrict__ xwf, const float* __restrict__ xwi,
    const float* __restrict__ xwc, const float* __restrict__ xwo,
    const float* __restrict__ bfv, const float* __restrict__ biv,
    const float* __restrict__ bcv, const float* __restrict__ bov,
    const int* __restrict__ tokens,
    float* __restrict__ outH, float* __restrict__ outC) {
  __shared__ __align__(16) unsigned char lds[147456];
  const int tid = threadIdx.x;
  const int wave = tid >> 6, lane = tid & 63;
  const int l15 = lane & 15, l4 = lane >> 4;
  const int wgc0 = blockIdx.x * 32;
  const int hbase0 = wgc0 >> 2;          // first of this WG's 8 h values
  const int mychunk = blockIdx.x >> 4;   // h-chunk this WG's H-slice belongs to
  const int brow = wave * 16 + l15;      // this lane's batch row

  auto xw_of = [&](int g) -> const float* {
    return g == 0 ? xwf : g == 1 ? xwi : g == 2 ? xwc : xwo;
  };
  auto b_of = [&](int g) -> const float* {
    return g == 0 ? bfv : g == 1 ? biv : g == 2 ? bcv : bov;
  };

  // ---- per-lane constants & persistent register state ----
  // mfma(W,H) D layout: col(batch) = l15, row(gate-col) = l4*4 + r.
  // WG cols (c = h*4+g): tile ni covers h = hbase0 + ni*4 + l4, gate = r.
  int hL[2];
  float bias8[2][4], Creg[2], xg[2][4], xgn[2][4];
#pragma unroll
  for (int ni = 0; ni < 2; ++ni) {
    hL[ni] = hbase0 + ni * 4 + l4;
#pragma unroll
    for (int r = 0; r < 4; ++r) bias8[ni][r] = b_of(r)[hL[ni]];
    Creg[ni] = C0[(size_t)brow * 1024 + hL[ni]];
  }
  {
    const int tk = tokens[brow * T_ + 0];
#pragma unroll
    for (int ni = 0; ni < 2; ++ni)
#pragma unroll
      for (int r = 0; r < 4; ++r)
        xg[ni][r] = xw_of(r)[(size_t)tk * 1024 + hL[ni]];
  }

  // ---- stage W-slice into LDS (once), pre-swizzled source ----
  {
    const char* Wb = (const char*)(Wcat + (size_t)wgc0 * 1024);
#pragma unroll
    for (int it = 0; it < 16; ++it) {
      const int D = it * 4096 + wave * 1024 + lane * 16;
      const int row = D >> 11, off = D & 2047;
      const int so = off ^ ((row & 7) << 4);
      gload_lds16(Wb + (size_t)row * 2048 + so, &lds[it * 4096 + wave * 1024]);
    }
  }
  asm volatile("s_waitcnt vmcnt(0)" ::: "memory");
  __syncthreads();

  // PER-WAVE staging: wave w stages its own 16 rows of chunk c (A ring),
  // NORMAL cached loads (L2-shared within the XCD).
  auto stageA = [&](int buf, int c, const char* Hsrc) {
#pragma unroll
    for (int it2 = 0; it2 < 4; ++it2) {
      const int row = wave * 16 + it2 * 4 + l4;       // row this lane loads
      const int so = (l15 * 16) ^ ((row & 7) << 4);   // pre-swizzled source
      gload_lds16(Hsrc + (size_t)row * 2048 + c * 256 + so,
                  &lds[AOFF + buf * 16384 + wave * 4096 + it2 * 1024]);
    }
  };

  const int bswz = (l15 & 7) << 4;
  f32x4 acc[2];
  const f32x4 zz = {0.f, 0.f, 0.f, 0.f};

#pragma unroll 1
  for (int t = 0; t < T_; ++t) {
    if (t > 0) poll8(cnt, (unsigned int)(16 * t), lane);   // H_t fully ready

    const char* Hs = (const char*)(Hbuf + (size_t)t * 65536);
    // prologue stages: chunks 0..3 -> bufs 0..3 (16 loads/wave)
    stageA(0, 0, Hs);
    stageA(1, 1, Hs);
    stageA(2, 2, Hs);
    stageA(3, 3, Hs);

    // UNCONDITIONAL token load (wrapped; unused value at t=T-1) pinned AFTER
    // the stages so the per-step vmcnt FIFO is identical at every t.
    __builtin_amdgcn_sched_barrier(0);
    int tok2 = tokens[brow * T_ + ((t + 1) & (T_ - 1))];
    __builtin_amdgcn_sched_barrier(0);

    acc[0] = zz; acc[1] = zz;
    // Barrier-free K loop. Per-wave FIFO: [xgn x8 oldest][S0..S3 x16][tok x1]
    // then +4 per in-loop stage. Newer-than-chunk-c at its wait:
    // c<4: (3-c)*4 + 1 + 4c = 13; c=4: 12; c=5: 8; c=6: 4; c=7: 0.
#pragma unroll
    for (int c = 0; c < 8; ++c) {
      if (c < 4)       asm volatile("s_waitcnt vmcnt(13)" ::: "memory");
      else if (c == 4) asm volatile("s_waitcnt vmcnt(12)" ::: "memory");
      else if (c == 5) asm volatile("s_waitcnt vmcnt(8)" ::: "memory");
      else if (c == 6) asm volatile("s_waitcnt vmcnt(4)" ::: "memory");
      else             asm volatile("s_waitcnt vmcnt(0)" ::: "memory");
      __builtin_amdgcn_sched_barrier(0);
      if (c < 4) stageA((c + 4) % 5, c + 4, Hs);
      __builtin_amdgcn_sched_barrier(0);
      {
        const int abase = AOFF + (c % 5) * 16384;
        const int abyte = abase + brow * 256;           // brow = wave*16+l15
        const int aswz = (brow & 7) << 4;
#pragma unroll
        for (int ks = 0; ks < 4; ++ks) {
          const int koff = ks * 64 + l4 * 16;
          short8 a  = *(const short8*)&lds[abyte + (koff ^ aswz)];            // H frag (B-op)
          short8 b0 = *(const short8*)&lds[(size_t)l15 * 2048 + ((c * 256 + koff) ^ bswz)];        // W frag (A-op), tile 0
          short8 b1 = *(const short8*)&lds[(size_t)(16 + l15) * 2048 + ((c * 256 + koff) ^ bswz)]; // W frag, tile 1
          acc[0] = __builtin_amdgcn_mfma_f32_16x16x32_bf16(b0, a, acc[0], 0, 0, 0);
          acc[1] = __builtin_amdgcn_mfma_f32_16x16x32_bf16(b1, a, acc[1], 0, 0, 0);
        }
      }
      __builtin_amdgcn_sched_barrier(0);
    }

    // xg for this step: t=0 preloaded; t>0 from prefetch issued last iteration
    if (t > 0) {
#pragma unroll
      for (int ni = 0; ni < 2; ++ni)
#pragma unroll
        for (int r = 0; r < 4; ++r) xg[ni][r] = xgn[ni][r];
    }

    // ---- epilogue: per lane, acc[ni][r] = gate r (f,i,c,o) of (brow, hL[ni])
    unsigned short* Hout = Hbuf + (size_t)(t + 1) * 65536;
    unsigned int dat32[2][2];
#pragma unroll
    for (int ni = 0; ni < 2; ++ni) {
      const f32x4 v = acc[ni];
      const float pre0 = v[0] + xg[ni][0] + bias8[ni][0];
      const float pre1 = v[1] + xg[ni][1] + bias8[ni][1];
      const float pre2 = v[2] + xg[ni][2] + bias8[ni][2];
      const float pre3 = v[3] + xg[ni][3] + bias8[ni][3];
      const float pf = 1.f / (1.f + __expf(-pre0));
      const float pi = 1.f / (1.f + __expf(-pre1));
      const float e2 = __expf(2.f * pre2);
      const float pc = (e2 - 1.f) / (e2 + 1.f);
      const float po = 1.f / (1.f + __expf(-pre3));
      const float cn = pf * Creg[ni] + pi * pc;
      Creg[ni] = cn;
      const float hv = po * cn;
      const unsigned int sbf = f2bf(hv);
      // pack 4 h (l4 groups, lane strides of 16) into 2 dwords on l4==0
      const unsigned int p = sbf | (((unsigned int)__shfl_down(sbf, 16)) << 16);
      dat32[ni][0] = p;
      dat32[ni][1] = __shfl_down(p, 32);
      if (t == T_ - 1) {
        const size_t idx = (size_t)brow * 1024 + hL[ni];
        outH[idx] = hv; outC[idx] = cn;
      }
    }
    if (l4 == 0) {   // lanes 0..15: one 16B store covers h hbase0..hbase0+7
      uint4v dat;
      dat.x = dat32[0][0]; dat.y = dat32[0][1];
      dat.z = dat32[1][0]; dat.w = dat32[1][1];
      const unsigned long long addr =
          (unsigned long long)(Hout + (size_t)brow * 1024 + hbase0);
      asm volatile("global_store_dwordx4 %0, %1, off sc0 sc1"
                   :: "v"(addr), "v"(dat) : "memory");
    }

    if (t < T_ - 1) {
      // ---- arrive: drain H stores (all waves), one relaxed add per WG ----
      asm volatile("s_waitcnt vmcnt(0)" ::: "memory");
      __syncthreads();
      if (tid == 0)
        __hip_atomic_fetch_add(cnt + 16 * mychunk, 1u, __ATOMIC_RELAXED,
                               __HIP_MEMORY_SCOPE_AGENT);

      // prefetch next-step x-gather (after arrival so it never delays it)
#pragma unroll
      for (int ni = 0; ni < 2; ++ni)
#pragma unroll
        for (int r = 0; r < 4; ++r)
          xgn[ni][r] = xw_of(r)[(size_t)tok2 * 1024 + hL[ni]];
    }
  }
}

// ---------------------------------------------------------------------------
// Y = Hseq(16384x1024 bf16) @ ywT^T + bias -> fp32. m97-style 128x128, BK=32.
// grid: 4096 WGs (tm = id>>5, tn = id&31), 256 thr, waves 2x2, wave tile 64x64.
// ---------------------------------------------------------------------------
__launch_bounds__(256, 1)
__global__ void out_gemm_kernel(const unsigned short* __restrict__ A,   // [16384][1024] bf16
                                const unsigned short* __restrict__ Bw,  // ywT [4096][1024] bf16
                                const float* __restrict__ bias,         // [4096]
                                float* __restrict__ Yout) {             // [16384][4096] f32
  __shared__ unsigned char Ash[2][8192];   // 128 rows x 64B, XOR-swizzled
  __shared__ unsigned char Bsh[2][8192];
  const int tid = threadIdx.x;
  const int wave = tid >> 6, lane = tid & 63;
  const int wm = wave >> 1, wn = wave & 1;
  const int bid = blockIdx.x;
  const int tn = bid & 31, tm = bid >> 5;

  const char* Agb = (const char*)(A + (size_t)tm * 128 * 1024);
  const char* Bgb = (const char*)(Bw + (size_t)tn * 128 * 1024);

  f32x4 acc[4][4];
  const f32x4 zz = {0.f, 0.f, 0.f, 0.f};
#pragma unroll
  for (int mi = 0; mi < 4; ++mi)
#pragma unroll
    for (int ni = 0; ni < 4; ++ni) acc[mi][ni] = zz;

  auto stage = [&](int buf, int kc) {
#pragma unroll
    for (int j = 0; j < 2; ++j) {
      const int wbase = wave * 2048 + j * 1024;
      const int D = wbase + lane * 16;
      const int row = D >> 6, off = D & 63;
      const int so = off ^ ((row & 3) << 4);
      gload_lds16(Agb + (size_t)row * 2048 + kc * 64 + so, &Ash[buf][wbase]);
      gload_lds16(Bgb + (size_t)row * 2048 + kc * 64 + so, &Bsh[buf][wbase]);
    }
  };

  stage(0, 0);
  __syncthreads();

#pragma unroll 1
  for (int kc = 0; kc < 32; ++kc) {
    const int cur = kc & 1;
    if (kc < 31) stage(cur ^ 1, kc + 1);
    short8 a[4], b[4];
#pragma unroll
    for (int mi = 0; mi < 4; ++mi) {
      const int row = wm * 64 + mi * 16 + (lane & 15);
      const int off = ((lane >> 4) * 16) ^ ((row & 3) << 4);
      a[mi] = *(const short8*)&Ash[cur][row * 64 + off];
    }
#pragma unroll
    for (int ni = 0; ni < 4; ++ni) {
      const int row = wn * 64 + ni * 16 + (lane & 15);
      const int off = ((lane >> 4) * 16) ^ ((row & 3) << 4);
      b[ni] = *(const short8*)&Bsh[cur][row * 64 + off];
    }
#pragma unroll
    for (int mi = 0; mi < 4; ++mi)
#pragma unroll
      for (int ni = 0; ni < 4; ++ni)
        acc[mi][ni] = __builtin_amdgcn_mfma_f32_16x16x32_bf16(a[mi], b[ni], acc[mi][ni], 0, 0, 0);
    __syncthreads();
  }

  const int l15 = lane & 15, l4 = lane >> 4;
#pragma unroll
  for (int ni = 0; ni < 4; ++ni) {
    const int n = tn * 128 + wn * 64 + ni * 16 + l15;
    const float bv = bias[n];
#pragma unroll
    for (int mi = 0; mi < 4; ++mi) {
#pragma unroll
      for (int r = 0; r < 4; ++r) {
        const int m = tm * 128 + wm * 64 + mi * 16 + l4 * 4 + r;
        Yout[(size_t)m * 4096 + n] = acc[mi][ni][r] + bv;
      }
    }
  }
}

// ---------------------------------------------------------------------------
extern "C" void kernel_launch(void* const* d_in, const int* in_sizes, int n_in,
                              void* d_out, int out_size, void* d_ws, size_t ws_size,
                              hipStream_t stream) {
  const int* tokens   = (const int*)d_in[0];
  const float* H0     = (const float*)d_in[1];
  const float* C0     = (const float*)d_in[2];
  const float* f_w_xh = (const float*)d_in[3];
  const float* f_w_hh = (const float*)d_in[4];
  const float* f_b    = (const float*)d_in[5];
  const float* i_w_xh = (const float*)d_in[6];
  const float* i_w_hh = (const float*)d_in[7];
  const float* i_b    = (const float*)d_in[8];
  const float* c_w_xh = (const float*)d_in[9];
  const float* c_w_hh = (const float*)d_in[10];
  const float* c_b    = (const float*)d_in[11];
  const float* o_w_xh = (const float*)d_in[12];
  const float* o_w_hh = (const float*)d_in[13];
  const float* o_b    = (const float*)d_in[14];
  const float* y_w_ho = (const float*)d_in[15];
  const float* y_b_o  = (const float*)d_in[16];

  char* ws = (char*)d_ws;
  unsigned short* Wcat = (unsigned short*)ws;                         // 8 MB
  unsigned short* ywT  = (unsigned short*)(ws + (size_t)(8u << 20));  // 8 MB
  unsigned short* Hbuf = (unsigned short*)(ws + (size_t)(16u << 20)); // 257*65536*2 B
  unsigned int* cnt = (unsigned int*)(ws + (size_t)(16u << 20) + (size_t)257 * 65536 * 2);
  const size_t needed = (size_t)(16u << 20) + (size_t)257 * 65536 * 2 + 1024;
  if (ws_size < needed) return;  // workspace too small: fail visibly

  const dim3 thr(256);
  hipLaunchKernelGGL(transpose_bf16_kernel, dim3(16, 16), thr, 0, stream, f_w_hh, 1024, Wcat, 4, 0);
  hipLaunchKernelGGL(transpose_bf16_kernel, dim3(16, 16), thr, 0, stream, i_w_hh, 1024, Wcat, 4, 1);
  hipLaunchKernelGGL(transpose_bf16_kernel, dim3(16, 16), thr, 0, stream, c_w_hh, 1024, Wcat, 4, 2);
  hipLaunchKernelGGL(transpose_bf16_kernel, dim3(16, 16), thr, 0, stream, o_w_hh, 1024, Wcat, 4, 3);
  hipLaunchKernelGGL(transpose_bf16_kernel, dim3(16, 64), thr, 0, stream, y_w_ho, 4096, ywT, 1, 0);
  hipLaunchKernelGGL(init_kernel, dim3(256), thr, 0, stream, H0, Hbuf, cnt);

  float* outH = (float*)d_out + (size_t)T_ * B_ * V_;
  hipLaunchKernelGGL(lstm_persistent_kernel, dim3(NWG), thr, 0, stream,
                     Wcat, Hbuf, cnt, C0,
                     f_w_xh, i_w_xh, c_w_xh, o_w_xh,
                     f_b, i_b, c_b, o_b,
                     tokens, outH, outH + 65536);

  hipLaunchKernelGGL(out_gemm_kernel, dim3(4096), thr, 0, stream,
                     Hbuf + 65536, ywT, y_b_o, (float*)d_out);
}

// Round 12
// 1346.837 us; speedup vs baseline: 1.7513x; 1.1852x over previous
//
#include <hip/hip_runtime.h>
#include <stdint.h>
#include <stddef.h>

// LSTM: B=64, H=1024, V=4096, T=256
// Phase 0: transpose weights to bf16 k-contiguous layouts (Wcat c=h*4+g, ywT).
// Phase 1: persistent recurrence kernel, 128 WGs x 256 thr (1 WG/CU, 144KB LDS):
//   - W-slice (32 gate-cols, 64KB) resident in LDS.
//   - mfma(W,H): D rows = gate-cols, cols = batch; r=0..3 = f,i,c,o of one h
//     in one lane (round-11 epilogue: 8 exp/lane, one 16B H-store/row).
//   - A (H rows) streamed via 5-buf LDS ring, PER-WAVE staging, normal cached
//     loads; H stores sc0|sc1 (write-through IF).
//   - Sync (round-12): WRITE-ONLY per-WAVE arrivals. arrival[wg*4+wave] = t+1
//     (plain sc0sc1 store, monotone, no RMW chain) after the wave's own
//     vmcnt(0) drain. NO per-step __syncthreads (waves touch only private
//     ring sections + read-only W). Poll: each wave reads all 512 slots
//     coalesced (2x dwordx4 sc0sc1 per lane) until __all(>= t).
//   - Barrier-free K loop; per-wave vmcnt FIFO 13/13/13/13/12/8/4/0 (re-valid
//     at every t: poll's internal vmcnt(0) rebaselines the FIFO each step).
// Phase 2: separate 16384x4096x1024 bf16 GEMM for Y.
// Workspace: WcatT 8MB | ywT 8MB | Hbuf (257*64*1024 bf16) 33.7MB | arrival 2KB

#define B_ 64
#define H_ 1024
#define V_ 4096
#define T_ 256
#define NWG 128

typedef __attribute__((ext_vector_type(8))) short short8;
typedef __attribute__((ext_vector_type(4))) float f32x4;
typedef __attribute__((ext_vector_type(4))) float float4_;
typedef __attribute__((ext_vector_type(4))) unsigned int uint4v;

static __device__ __forceinline__ unsigned short f2bf(float f) {
  union { float f; unsigned int u; } v; v.f = f;
  unsigned int u = v.u;
  unsigned int r = (u + 0x7fffu + ((u >> 16) & 1u)) >> 16;   // round-to-nearest-even
  return (unsigned short)r;
}

static __device__ __forceinline__ void gload_lds16(const void* g, void* l) {
  // async global->LDS, 16B per lane; LDS dest = wave-uniform base + lane*16
  __builtin_amdgcn_global_load_lds((const __attribute__((address_space(1))) unsigned int*)g,
                                   (__attribute__((address_space(3))) unsigned int*)l,
                                   16, 0, 0);
}

static __device__ __forceinline__ void sc_store_u32(unsigned int* p, unsigned int v) {
  asm volatile("global_store_dword %0, %1, off sc0 sc1"
               :: "v"((unsigned long long)p), "v"(v) : "memory");
}

// wave poll: lane l reads arrival slots [4l..4l+3] and [256+4l..256+4l+3]
// (512 slots total) at the IF (sc0sc1), exits when all >= tgt.
static __device__ __forceinline__ void pollw(const unsigned int* arr, unsigned int tgt, int lane) {
  const unsigned long long a0 = (unsigned long long)arr + (unsigned long long)lane * 16;
  const unsigned long long a1 = a0 + 1024;
  while (true) {
    uint4v v0, v1;
    asm volatile("global_load_dwordx4 %0, %2, off sc0 sc1\n\t"
                 "global_load_dwordx4 %1, %3, off sc0 sc1\n\t"
                 "s_waitcnt vmcnt(0)"
                 : "=&v"(v0), "=&v"(v1) : "v"(a0), "v"(a1) : "memory");
    const bool ok = v0[0] >= tgt && v0[1] >= tgt && v0[2] >= tgt && v0[3] >= tgt &&
                    v1[0] >= tgt && v1[1] >= tgt && v1[2] >= tgt && v1[3] >= tgt;
    if (__all(ok)) break;
  }
  asm volatile("" ::: "memory");           // no load hoisting above the poll
  __builtin_amdgcn_sched_barrier(0);
}

// ---------------------------------------------------------------------------
// Tiled transpose fp32 (K x C) -> bf16 rows: dst[c = col*c_mul + c_add][k]
// grid: (K/64, C/64), 256 threads
// ---------------------------------------------------------------------------
__global__ void transpose_bf16_kernel(const float* __restrict__ src, int src_cols,
                                      unsigned short* __restrict__ dst,
                                      int c_mul, int c_add) {
  __shared__ float tile[64][65];
  const int k0 = blockIdx.x * 64, h0 = blockIdx.y * 64;
  const int t = threadIdx.x;
  {
    const int kk = t >> 2, seg = (t & 3) * 16;
    const float* s = src + (size_t)(k0 + kk) * src_cols + h0 + seg;
#pragma unroll
    for (int j = 0; j < 16; j += 4) {
      float4_ v = *(const float4_*)(s + j);
      tile[kk][seg + j + 0] = v[0];
      tile[kk][seg + j + 1] = v[1];
      tile[kk][seg + j + 2] = v[2];
      tile[kk][seg + j + 3] = v[3];
    }
  }
  __syncthreads();
  {
    const int hh = t >> 2, ks = (t & 3) * 16;
    const int c = (h0 + hh) * c_mul + c_add;
    short8 p0, p1;
#pragma unroll
    for (int j = 0; j < 8; ++j) {
      p0[j] = (short)f2bf(tile[ks + j][hh]);
      p1[j] = (short)f2bf(tile[ks + 8 + j][hh]);
    }
    unsigned short* d = dst + (size_t)c * 1024 + k0 + ks;
    *(short8*)(d) = p0;
    *(short8*)(d + 8) = p1;
  }
}

// ---------------------------------------------------------------------------
__global__ void init_kernel(const float* __restrict__ H0,
                            unsigned short* __restrict__ Hbuf0,
                            unsigned int* __restrict__ arr) {
  const int i = blockIdx.x * 256 + threadIdx.x;  // 65536
  Hbuf0[i] = f2bf(H0[i]);
  // zero all 512 arrival slots AT THE IF (sc0sc1): normal stores could sit
  // dirty in L2 and be invisible to the sc0sc1 pollers on graph replay.
  if (i < 512) sc_store_u32(arr + i, 0u);
}

// ---------------------------------------------------------------------------
// Persistent LSTM recurrence. 128 WGs x 256 thr (4 waves).
// LDS: W 64KB @0 | ring 5x16KB @65536 = 144KB.
// ---------------------------------------------------------------------------
#define AOFF 65536

__launch_bounds__(256, 1)
__global__ void lstm_persistent_kernel(
    const unsigned short* __restrict__ Wcat,   // [4096][1024] bf16
    unsigned short* __restrict__ Hbuf,         // [257][64][1024] bf16
    unsigned int* __restrict__ arr,            // [512] per-wave arrival slots
    const float* __restrict__ C0,              // [64][1024] f32
    const float* __restrict__ xwf, const float* __restrict__ xwi,
    const float* __restrict__ xwc, const float* __restrict__ xwo,
    const float* __restrict__ bfv, const float* __restrict__ biv,
    const float* __restrict__ bcv, const float* __restrict__ bov,
    const int* __restrict__ tokens,
    float* __restrict__ outH, float* __restrict__ outC) {
  __shared__ __align__(16) unsigned char lds[147456];
  const int tid = threadIdx.x;
  const int wave = tid >> 6, lane = tid & 63;
  const int l15 = lane & 15, l4 = lane >> 4;
  const int wgc0 = blockIdx.x * 32;
  const int hbase0 = wgc0 >> 2;          // first of this WG's 8 h values
  const int brow = wave * 16 + l15;      // this lane's batch row
  unsigned int* myslot = arr + blockIdx.x * 4 + wave;

  auto xw_of = [&](int g) -> const float* {
    return g == 0 ? xwf : g == 1 ? xwi : g == 2 ? xwc : xwo;
  };
  auto b_of = [&](int g) -> const float* {
    return g == 0 ? bfv : g == 1 ? biv : g == 2 ? bcv : bov;
  };

  // ---- per-lane constants & persistent register state ----
  // mfma(W,H) D layout: col(batch) = l15, row(gate-col) = l4*4 + r.
  // WG cols (c = h*4+g): tile ni covers h = hbase0 + ni*4 + l4, gate = r.
  int hL[2];
  float bias8[2][4], Creg[2], xg[2][4], xgn[2][4];
#pragma unroll
  for (int ni = 0; ni < 2; ++ni) {
    hL[ni] = hbase0 + ni * 4 + l4;
#pragma unroll
    for (int r = 0; r < 4; ++r) bias8[ni][r] = b_of(r)[hL[ni]];
    Creg[ni] = C0[(size_t)brow * 1024 + hL[ni]];
  }
  {
    const int tk = tokens[brow * T_ + 0];
#pragma unroll
    for (int ni = 0; ni < 2; ++ni)
#pragma unroll
      for (int r = 0; r < 4; ++r)
        xg[ni][r] = xw_of(r)[(size_t)tk * 1024 + hL[ni]];
  }

  // ---- stage W-slice into LDS (once), pre-swizzled source ----
  {
    const char* Wb = (const char*)(Wcat + (size_t)wgc0 * 1024);
#pragma unroll
    for (int it = 0; it < 16; ++it) {
      const int D = it * 4096 + wave * 1024 + lane * 16;
      const int row = D >> 11, off = D & 2047;
      const int so = off ^ ((row & 7) << 4);
      gload_lds16(Wb + (size_t)row * 2048 + so, &lds[it * 4096 + wave * 1024]);
    }
  }
  asm volatile("s_waitcnt vmcnt(0)" ::: "memory");
  __syncthreads();   // W visible to all waves (the ONLY workgroup barrier)

  // PER-WAVE staging: wave w stages its own 16 rows of chunk c (A ring),
  // normal cached loads (L2-shared within the XCD).
  auto stageA = [&](int buf, int c, const char* Hsrc) {
#pragma unroll
    for (int it2 = 0; it2 < 4; ++it2) {
      const int row = wave * 16 + it2 * 4 + l4;       // row this lane loads
      const int so = (l15 * 16) ^ ((row & 7) << 4);   // pre-swizzled source
      gload_lds16(Hsrc + (size_t)row * 2048 + c * 256 + so,
                  &lds[AOFF + buf * 16384 + wave * 4096 + it2 * 1024]);
    }
  };

  const int bswz = (l15 & 7) << 4;
  f32x4 acc[2];
  const f32x4 zz = {0.f, 0.f, 0.f, 0.f};

#pragma unroll 1
  for (int t = 0; t < T_; ++t) {
    if (t > 0) pollw(arr, (unsigned int)t, lane);   // all waves finished t-1

    const char* Hs = (const char*)(Hbuf + (size_t)t * 65536);
    // prologue stages: chunks 0..3 -> bufs 0..3 (16 loads/wave)
    stageA(0, 0, Hs);
    stageA(1, 1, Hs);
    stageA(2, 2, Hs);
    stageA(3, 3, Hs);

    // UNCONDITIONAL token load (wrapped; value unused at t=T-1) pinned AFTER
    // the stages so the per-step vmcnt FIFO is identical at every t.
    __builtin_amdgcn_sched_barrier(0);
    int tok2 = tokens[brow * T_ + ((t + 1) & (T_ - 1))];
    __builtin_amdgcn_sched_barrier(0);

    acc[0] = zz; acc[1] = zz;
    // Barrier-free K loop. Per-wave FIFO after poll drain: [S0..S3 x16][tok]
    // = 17 outstanding at c=0's wait; +4 per in-loop stage keeps 17 at each
    // c<4 wait -> vmcnt(13) retires exactly S_c; then 12/8/4/0.
#pragma unroll
    for (int c = 0; c < 8; ++c) {
      if (c < 4)       asm volatile("s_waitcnt vmcnt(13)" ::: "memory");
      else if (c == 4) asm volatile("s_waitcnt vmcnt(12)" ::: "memory");
      else if (c == 5) asm volatile("s_waitcnt vmcnt(8)" ::: "memory");
      else if (c == 6) asm volatile("s_waitcnt vmcnt(4)" ::: "memory");
      else             asm volatile("s_waitcnt vmcnt(0)" ::: "memory");
      __builtin_amdgcn_sched_barrier(0);
      if (c < 4) stageA((c + 4) % 5, c + 4, Hs);
      __builtin_amdgcn_sched_barrier(0);
      {
        const int abase = AOFF + (c % 5) * 16384;
        const int abyte = abase + brow * 256;           // brow = wave*16+l15
        const int aswz = (brow & 7) << 4;
#pragma unroll
        for (int ks = 0; ks < 4; ++ks) {
          const int koff = ks * 64 + l4 * 16;
          short8 a  = *(const short8*)&lds[abyte + (koff ^ aswz)];            // H frag (B-op)
          short8 b0 = *(const short8*)&lds[(size_t)l15 * 2048 + ((c * 256 + koff) ^ bswz)];        // W frag (A-op), tile 0
          short8 b1 = *(const short8*)&lds[(size_t)(16 + l15) * 2048 + ((c * 256 + koff) ^ bswz)]; // W frag, tile 1
          acc[0] = __builtin_amdgcn_mfma_f32_16x16x32_bf16(b0, a, acc[0], 0, 0, 0);
          acc[1] = __builtin_amdgcn_mfma_f32_16x16x32_bf16(b1, a, acc[1], 0, 0, 0);
        }
      }
      __builtin_amdgcn_sched_barrier(0);
    }

    // xg for this step: t=0 preloaded; t>0 from prefetch issued last iteration
    if (t > 0) {
#pragma unroll
      for (int ni = 0; ni < 2; ++ni)
#pragma unroll
        for (int r = 0; r < 4; ++r) xg[ni][r] = xgn[ni][r];
    }

    // ---- epilogue: per lane, acc[ni][r] = gate r (f,i,c,o) of (brow, hL[ni])
    unsigned short* Hout = Hbuf + (size_t)(t + 1) * 65536;
    unsigned int dat32[2][2];
#pragma unroll
    for (int ni = 0; ni < 2; ++ni) {
      const f32x4 v = acc[ni];
      const float pre0 = v[0] + xg[ni][0] + bias8[ni][0];
      const float pre1 = v[1] + xg[ni][1] + bias8[ni][1];
      const float pre2 = v[2] + xg[ni][2] + bias8[ni][2];
      const float pre3 = v[3] + xg[ni][3] + bias8[ni][3];
      const float pf = 1.f / (1.f + __expf(-pre0));
      const float pi = 1.f / (1.f + __expf(-pre1));
      const float e2 = __expf(2.f * pre2);
      const float pc = (e2 - 1.f) / (e2 + 1.f);
      const float po = 1.f / (1.f + __expf(-pre3));
      const float cn = pf * Creg[ni] + pi * pc;
      Creg[ni] = cn;
      const float hv = po * cn;
      const unsigned int sbf = f2bf(hv);
      // pack 4 h (l4 groups, lane strides of 16) into 2 dwords on l4==0
      const unsigned int p = sbf | (((unsigned int)__shfl_down(sbf, 16)) << 16);
      dat32[ni][0] = p;
      dat32[ni][1] = __shfl_down(p, 32);
      if (t == T_ - 1) {
        const size_t idx = (size_t)brow * 1024 + hL[ni];
        outH[idx] = hv; outC[idx] = cn;
      }
    }
    if (l4 == 0) {   // lanes 0..15: one 16B store covers h hbase0..hbase0+7
      uint4v dat;
      dat.x = dat32[0][0]; dat.y = dat32[0][1];
      dat.z = dat32[1][0]; dat.w = dat32[1][1];
      const unsigned long long addr =
          (unsigned long long)(Hout + (size_t)brow * 1024 + hbase0);
      asm volatile("global_store_dwordx4 %0, %1, off sc0 sc1"
                   :: "v"(addr), "v"(dat) : "memory");
    }

    if (t < T_ - 1) {
      // ---- arrive (per wave, no WG barrier): own H stores drained -> slot
      asm volatile("s_waitcnt vmcnt(0)" ::: "memory");
      if (lane == 0) sc_store_u32(myslot, (unsigned int)(t + 1));

      // prefetch next-step x-gather (after arrival so it never delays it)
#pragma unroll
      for (int ni = 0; ni < 2; ++ni)
#pragma unroll
        for (int r = 0; r < 4; ++r)
          xgn[ni][r] = xw_of(r)[(size_t)tok2 * 1024 + hL[ni]];
    }
  }
}

// ---------------------------------------------------------------------------
// Y = Hseq(16384x1024 bf16) @ ywT^T + bias -> fp32. m97-style 128x128, BK=32.
// grid: 4096 WGs (tm = id>>5, tn = id&31), 256 thr, waves 2x2, wave tile 64x64.
// ---------------------------------------------------------------------------
__launch_bounds__(256, 1)
__global__ void out_gemm_kernel(const unsigned short* __restrict__ A,   // [16384][1024] bf16
                                const unsigned short* __restrict__ Bw,  // ywT [4096][1024] bf16
                                const float* __restrict__ bias,         // [4096]
                                float* __restrict__ Yout) {             // [16384][4096] f32
  __shared__ unsigned char Ash[2][8192];   // 128 rows x 64B, XOR-swizzled
  __shared__ unsigned char Bsh[2][8192];
  const int tid = threadIdx.x;
  const int wave = tid >> 6, lane = tid & 63;
  const int wm = wave >> 1, wn = wave & 1;
  const int bid = blockIdx.x;
  const int tn = bid & 31, tm = bid >> 5;

  const char* Agb = (const char*)(A + (size_t)tm * 128 * 1024);
  const char* Bgb = (const char*)(Bw + (size_t)tn * 128 * 1024);

  f32x4 acc[4][4];
  const f32x4 zz = {0.f, 0.f, 0.f, 0.f};
#pragma unroll
  for (int mi = 0; mi < 4; ++mi)
#pragma unroll
    for (int ni = 0; ni < 4; ++ni) acc[mi][ni] = zz;

  auto stage = [&](int buf, int kc) {
#pragma unroll
    for (int j = 0; j < 2; ++j) {
      const int wbase = wave * 2048 + j * 1024;
      const int D = wbase + lane * 16;
      const int row = D >> 6, off = D & 63;
      const int so = off ^ ((row & 3) << 4);
      gload_lds16(Agb + (size_t)row * 2048 + kc * 64 + so, &Ash[buf][wbase]);
      gload_lds16(Bgb + (size_t)row * 2048 + kc * 64 + so, &Bsh[buf][wbase]);
    }
  };

  stage(0, 0);
  __syncthreads();

#pragma unroll 1
  for (int kc = 0; kc < 32; ++kc) {
    const int cur = kc & 1;
    if (kc < 31) stage(cur ^ 1, kc + 1);
    short8 a[4], b[4];
#pragma unroll
    for (int mi = 0; mi < 4; ++mi) {
      const int row = wm * 64 + mi * 16 + (lane & 15);
      const int off = ((lane >> 4) * 16) ^ ((row & 3) << 4);
      a[mi] = *(const short8*)&Ash[cur][row * 64 + off];
    }
#pragma unroll
    for (int ni = 0; ni < 4; ++ni) {
      const int row = wn * 64 + ni * 16 + (lane & 15);
      const int off = ((lane >> 4) * 16) ^ ((row & 3) << 4);
      b[ni] = *(const short8*)&Bsh[cur][row * 64 + off];
    }
#pragma unroll
    for (int mi = 0; mi < 4; ++mi)
#pragma unroll
      for (int ni = 0; ni < 4; ++ni)
        acc[mi][ni] = __builtin_amdgcn_mfma_f32_16x16x32_bf16(a[mi], b[ni], acc[mi][ni], 0, 0, 0);
    __syncthreads();
  }

  const int l15 = lane & 15, l4 = lane >> 4;
#pragma unroll
  for (int ni = 0; ni < 4; ++ni) {
    const int n = tn * 128 + wn * 64 + ni * 16 + l15;
    const float bv = bias[n];
#pragma unroll
    for (int mi = 0; mi < 4; ++mi) {
#pragma unroll
      for (int r = 0; r < 4; ++r) {
        const int m = tm * 128 + wm * 64 + mi * 16 + l4 * 4 + r;
        Yout[(size_t)m * 4096 + n] = acc[mi][ni][r] + bv;
      }
    }
  }
}

// ---------------------------------------------------------------------------
extern "C" void kernel_launch(void* const* d_in, const int* in_sizes, int n_in,
                              void* d_out, int out_size, void* d_ws, size_t ws_size,
                              hipStream_t stream) {
  const int* tokens   = (const int*)d_in[0];
  const float* H0     = (const float*)d_in[1];
  const float* C0     = (const float*)d_in[2];
  const float* f_w_xh = (const float*)d_in[3];
  const float* f_w_hh = (const float*)d_in[4];
  const float* f_b    = (const float*)d_in[5];
  const float* i_w_xh = (const float*)d_in[6];
  const float* i_w_hh = (const float*)d_in[7];
  const float* i_b    = (const float*)d_in[8];
  const float* c_w_xh = (const float*)d_in[9];
  const float* c_w_hh = (const float*)d_in[10];
  const float* c_b    = (const float*)d_in[11];
  const float* o_w_xh = (const float*)d_in[12];
  const float* o_w_hh = (const float*)d_in[13];
  const float* o_b    = (const float*)d_in[14];
  const float* y_w_ho = (const float*)d_in[15];
  const float* y_b_o  = (const float*)d_in[16];

  char* ws = (char*)d_ws;
  unsigned short* Wcat = (unsigned short*)ws;                         // 8 MB
  unsigned short* ywT  = (unsigned short*)(ws + (size_t)(8u << 20));  // 8 MB
  unsigned short* Hbuf = (unsigned short*)(ws + (size_t)(16u << 20)); // 257*65536*2 B
  unsigned int* arr = (unsigned int*)(ws + (size_t)(16u << 20) + (size_t)257 * 65536 * 2);
  const size_t needed = (size_t)(16u << 20) + (size_t)257 * 65536 * 2 + 2048;
  if (ws_size < needed) return;  // workspace too small: fail visibly

  const dim3 thr(256);
  hipLaunchKernelGGL(transpose_bf16_kernel, dim3(16, 16), thr, 0, stream, f_w_hh, 1024, Wcat, 4, 0);
  hipLaunchKernelGGL(transpose_bf16_kernel, dim3(16, 16), thr, 0, stream, i_w_hh, 1024, Wcat, 4, 1);
  hipLaunchKernelGGL(transpose_bf16_kernel, dim3(16, 16), thr, 0, stream, c_w_hh, 1024, Wcat, 4, 2);
  hipLaunchKernelGGL(transpose_bf16_kernel, dim3(16, 16), thr, 0, stream, o_w_hh, 1024, Wcat, 4, 3);
  hipLaunchKernelGGL(transpose_bf16_kernel, dim3(16, 64), thr, 0, stream, y_w_ho, 4096, ywT, 1, 0);
  hipLaunchKernelGGL(init_kernel, dim3(256), thr, 0, stream, H0, Hbuf, arr);

  float* outH = (float*)d_out + (size_t)T_ * B_ * V_;
  hipLaunchKernelGGL(lstm_persistent_kernel, dim3(NWG), thr, 0, stream,
                     Wcat, Hbuf, arr, C0,
                     f_w_xh, i_w_xh, c_w_xh, o_w_xh,
                     f_b, i_b, c_b, o_b,
                     tokens, outH, outH + 65536);

  hipLaunchKernelGGL(out_gemm_kernel, dim3(4096), thr, 0, stream,
                     Hbuf + 65536, ywT, y_b_o, (float*)d_out);
}